// Round 2
// baseline (744.451 us; speedup 1.0000x reference)
//
#include <hip/hip_runtime.h>
#include <stdint.h>

typedef __attribute__((ext_vector_type(8))) short short8;
typedef __attribute__((ext_vector_type(4))) float f32x4;
typedef __attribute__((ext_vector_type(2))) _Float16 half2_t;

#define DEV __device__ __forceinline__

DEV float bits2f(uint32_t u){ union{uint32_t u;float f;}v; v.u=u; return v.f; }
DEV float bf_lo(uint32_t w){ return bits2f(w<<16); }
DEV float bf_hi(uint32_t w){ return bits2f(w & 0xffff0000u); }
DEV float bf1(uint16_t s){ return bits2f(((uint32_t)s)<<16); }
DEV uint16_t f2bf(float f){ union{float f;uint32_t u;}v; v.f=f; uint32_t u=v.u;
  return (uint16_t)((u + 0x7fffu + ((u>>16)&1u))>>16); }
DEV uint32_t pk16(float a, float b){ union{_Float16 h[2]; uint32_t u;}v;
  v.h[0]=(_Float16)a; v.h[1]=(_Float16)b; return v.u; }
DEV half2_t h2(uint32_t u){ union{uint32_t u; half2_t h;}v; v.u=u; return v.h; }

DEV float ldval(const float* p, size_t i){ return p[i]; }
DEV float ldval(const uint16_t* p, size_t i){ return bf1(p[i]); }
DEV void stval(float* p, size_t i, float v){ p[i]=v; }
DEV void stval(uint16_t* p, size_t i, float v){ p[i]=f2bf(v); }

DEV float fdot2f(half2_t a, half2_t b, float c){
#if __has_builtin(__builtin_amdgcn_fdot2)
  return __builtin_amdgcn_fdot2(a,b,c,false);
#else
  return c + (float)a[0]*(float)b[0] + (float)a[1]*(float)b[1];
#endif
}

DEV void async16(const void* g, void* l){
#if __has_builtin(__builtin_amdgcn_global_load_lds)
  __builtin_amdgcn_global_load_lds((const __attribute__((address_space(1))) void*)g,
                                   (__attribute__((address_space(3))) void*)l, 16, 0, 0);
#else
  int lane = threadIdx.x & 63;
  *(uint4*)((char*)l + lane*16) = *(const uint4*)((const char*)g);
#endif
}

// ---------------------------------------------------------------------------
// GEMM: C[M,N] = A[M,K] @ Bt[N,K]^T + bias[N] (+ res[M,N]).  M = gridDim.y*128.
// A, Bt, res, C are bf16; bias fp32. m97 structure: 128x128 tile, BK=32.
// ---------------------------------------------------------------------------
__global__ __launch_bounds__(256) void gemm_bt(
    const uint16_t* __restrict__ A, const uint16_t* __restrict__ Bt,
    const float* __restrict__ bias, const uint16_t* __restrict__ res,
    uint16_t* __restrict__ C, int N, int K) {
  __shared__ uint16_t sA[128*32];
  __shared__ uint16_t sB[128*32];
  const int m0 = blockIdx.y*128, n0 = blockIdx.x*128;
  const int tid = threadIdx.x, wid = tid>>6, lane = tid&63;
  const int wm = (wid>>1)*64, wn = (wid&1)*64;
  f32x4 acc[4][4];
  #pragma unroll
  for (int a=0;a<4;a++)
    #pragma unroll
    for (int b=0;b<4;b++) acc[a][b] = (f32x4){0.f,0.f,0.f,0.f};
  const int lrow = lane>>2, lcol = (lane&3)*8;

  for (int k0 = 0; k0 < K; k0 += 32) {
    __syncthreads();
    #pragma unroll
    for (int j = 0; j < 2; ++j) {
      int r0 = wid*32 + j*16;
      async16(A  + (size_t)(m0 + r0 + lrow)*K + k0 + lcol, &sA[r0*32]);
      async16(Bt + (size_t)(n0 + r0 + lrow)*K + k0 + lcol, &sB[r0*32]);
    }
    __syncthreads();
    short8 af[4], bfv[4];
    #pragma unroll
    for (int t=0;t<4;t++) {
      af[t]  = *(const short8*)&sA[(wm + t*16 + (lane&15))*32 + (lane>>4)*8];
      bfv[t] = *(const short8*)&sB[(wn + t*16 + (lane&15))*32 + (lane>>4)*8];
    }
    #pragma unroll
    for (int mt=0;mt<4;mt++)
      #pragma unroll
      for (int nt=0;nt<4;nt++)
        acc[mt][nt] = __builtin_amdgcn_mfma_f32_16x16x32_bf16(af[mt], bfv[nt], acc[mt][nt], 0,0,0);
  }
  // epilogue: C/D layout col = lane&15, row = (lane>>4)*4 + reg
  const int cl = lane&15, rl = (lane>>4)*4;
  #pragma unroll
  for (int nt=0;nt<4;nt++) {
    int n = n0 + wn + nt*16 + cl;
    float bv = bias ? bias[n] : 0.f;
    #pragma unroll
    for (int mt=0;mt<4;mt++) {
      #pragma unroll
      for (int r=0;r<4;r++) {
        int m = m0 + wm + mt*16 + rl + r;
        float v = acc[mt][nt][r] + bv;
        if (res) v += bf1(res[(size_t)m*N + n]);
        C[(size_t)m*N + n] = f2bf(v);
      }
    }
  }
}

// ---------------------------------------------------------------------------
// LayerNorm over D=1024, one block (256 thr) per row. scale/bias fp32.
// ---------------------------------------------------------------------------
template<typename TI, typename TO>
__global__ __launch_bounds__(256) void ln_k(const TI* __restrict__ x,
    const float* __restrict__ sc, const float* __restrict__ bi,
    TO* __restrict__ out) {
  const int row = blockIdx.x, tid = threadIdx.x;
  const size_t base = (size_t)row*1024 + tid*4;
  float v0=ldval(x,base), v1=ldval(x,base+1), v2=ldval(x,base+2), v3=ldval(x,base+3);
  float s = v0+v1+v2+v3;
  float sq = v0*v0+v1*v1+v2*v2+v3*v3;
  #pragma unroll
  for (int off=32; off; off>>=1){ s += __shfl_xor(s,off); sq += __shfl_xor(sq,off); }
  __shared__ float red[8];
  int wid=tid>>6, lane=tid&63;
  if (lane==0){ red[wid]=s; red[4+wid]=sq; }
  __syncthreads();
  s = red[0]+red[1]+red[2]+red[3]; sq = red[4]+red[5]+red[6]+red[7];
  float mean = s*(1.f/1024.f);
  float var  = sq*(1.f/1024.f) - mean*mean;
  float inv  = rsqrtf(var + 1e-5f);
  int c = tid*4;
  stval(out, base,   (v0-mean)*inv*sc[c]   + bi[c]);
  stval(out, base+1, (v1-mean)*inv*sc[c+1] + bi[c+1]);
  stval(out, base+2, (v2-mean)*inv*sc[c+2] + bi[c+2]);
  stval(out, base+3, (v3-mean)*inv*sc[c+3] + bi[c+3]);
}

// ---------------------------------------------------------------------------
// Emformer mask closed form. Group ci in [0,8): queries = 32 summary (ci<7) +
// 128 body; keys = 32 summary (ci<7) + body window [max(128(ci-1),0),
// min(128(ci+1),1024)). Dense inside group. blk = ((b*16+h)*8+ci)*4+qg.
// qkv layout: bf16 rows [b*1248 + t][3072] = Q|K|V each 1024.
// ---------------------------------------------------------------------------
__global__ __launch_bounds__(256) void attn_scores(
    const uint32_t* __restrict__ qkv32, uint16_t* __restrict__ probs) {
  const int blk = blockIdx.x;
  const int qg = blk & 3, ci = (blk>>2)&7, hh = (blk>>5)&15, bb = blk>>9;
  const int sum_cnt = (ci<7)?32:0;
  const int bstart = (ci>=1)?128*(ci-1):0;
  const int bend = (ci==7)?1024:128*(ci+1);
  const int nk = sum_cnt + (bend - bstart);          // 160 / 288 / 256
  const int rowbase = bb*1248;
  __shared__ uint32_t K2[288*33];                    // f16 dim-pairs, row-per-key
  for (int idx = threadIdx.x; idx < nk*32; idx += 256) {
    int j = idx>>5, d2 = idx&31;
    int tk = (j < sum_cnt) ? (32*ci + j) : (224 + bstart + (j - sum_cnt));
    uint32_t u = qkv32[(size_t)(rowbase+tk)*1536 + 512 + hh*32 + d2];
    K2[j*33+d2] = pk16(bf_lo(u), bf_hi(u));
  }
  __syncthreads();
  const int wid = threadIdx.x>>6, lane = threadIdx.x&63;
  const int qbase = qg*40 + wid*10;
  const size_t pbase = (size_t)((bb*16+hh)*8 + ci)*160;

  for (int pp=0; pp<10; pp+=2) {
    int ql[2] = {qbase+pp, qbase+pp+1};
    half2_t qh0[32], qh1[32];
    {
      int tq0 = (ql[0]<32)?(32*ci+ql[0]):(224+128*ci+ql[0]-32);
      int tq1 = (ql[1]<32)?(32*ci+ql[1]):(224+128*ci+ql[1]-32);
      const uint32_t* p0 = qkv32 + (size_t)(rowbase+tq0)*1536 + hh*32;
      const uint32_t* p1 = qkv32 + (size_t)(rowbase+tq1)*1536 + hh*32;
      #pragma unroll
      for (int d2=0; d2<32; ++d2) {
        uint32_t u0=p0[d2]; qh0[d2]=h2(pk16(bf_lo(u0),bf_hi(u0)));
        uint32_t u1=p1[d2]; qh1[d2]=h2(pk16(bf_lo(u1),bf_hi(u1)));
      }
    }
    float sc0[5], sc1[5];
    #pragma unroll
    for (int g=0; g<5; ++g) { sc0[g]=-1e30f; sc1[g]=-1e30f; }
    #pragma unroll
    for (int g=0; g<5; ++g) {
      if (g*64 < nk) {
        int jl = g*64 + lane; bool ok = jl < nk; int jc = ok ? jl : 0;
        const uint32_t* kr = &K2[jc*33];
        float a0=0.f, a1=0.f;
        #pragma unroll
        for (int d2=0; d2<32; ++d2) {
          half2_t kh = h2(kr[d2]);
          a0 = fdot2f(kh, qh0[d2], a0);
          a1 = fdot2f(kh, qh1[d2], a1);
        }
        if (ok) { sc0[g] = a0*0.125f; sc1[g] = a1*0.125f; }
      }
    }
    #pragma unroll
    for (int qi=0; qi<2; ++qi) {
      float* sc = qi ? sc1 : sc0;
      float mx = -1e30f;
      #pragma unroll
      for (int g=0; g<5; ++g) mx = fmaxf(mx, sc[g]);
      #pragma unroll
      for (int off=32; off; off>>=1) mx = fmaxf(mx, __shfl_xor(mx,off));
      float sum = 0.f;
      #pragma unroll
      for (int g=0; g<5; ++g) { float p = __expf(sc[g]-mx); sc[g]=p; sum+=p; }
      #pragma unroll
      for (int off=32; off; off>>=1) sum += __shfl_xor(sum,off);
      float inv = 1.f/sum;
      bool vq = (ci<7) || (ql[qi]>=32);
      if (vq) {
        uint16_t* prow = probs + (pbase + ql[qi])*288;
        #pragma unroll
        for (int g=0; g<5; ++g) {
          int jl = g*64+lane;
          if (jl < nk) { union{_Float16 h; uint16_t u;}cv; cv.h=(_Float16)(sc[g]*inv); prow[jl]=cv.u; }
        }
      }
    }
  }
}

__global__ __launch_bounds__(256) void attn_pv(
    const uint32_t* __restrict__ qkv32, const uint32_t* __restrict__ probs32,
    const uint16_t* __restrict__ hres, uint16_t* __restrict__ attn_out) {
  const int blk = blockIdx.x;
  const int qg = blk & 3, ci = (blk>>2)&7, hh = (blk>>5)&15, bb = blk>>9;
  const int sum_cnt = (ci<7)?32:0;
  const int bstart = (ci>=1)?128*(ci-1):0;
  const int bend = (ci==7)?1024:128*(ci+1);
  const int nk = sum_cnt + (bend - bstart);
  const int rowbase = bb*1248;
  __shared__ uint32_t VT[64*147];     // V^T in f16, row stride 294 f16 (147 dw, odd -> no bank conflict)
  __shared__ uint32_t PL[40*144];     // probs rows for this block's 40 queries
  for (int idx = threadIdx.x; idx < nk*32; idx += 256) {
    int j = idx>>5, d2 = idx&31;
    int tk = (j < sum_cnt) ? (32*ci + j) : (224 + bstart + (j - sum_cnt));
    uint32_t u = qkv32[(size_t)(rowbase+tk)*1536 + 1024 + hh*32 + d2];
    uint16_t* vt16 = (uint16_t*)VT;
    union{_Float16 h; uint16_t u;}c0, c1;
    c0.h = (_Float16)bf_lo(u); c1.h = (_Float16)bf_hi(u);
    vt16[(2*d2)*294 + j]   = c0.u;
    vt16[(2*d2+1)*294 + j] = c1.u;
  }
  {
    const size_t pdw = ((size_t)((bb*16+hh)*8 + ci)*160 + qg*40)*144;
    for (int idx = threadIdx.x; idx < 40*144; idx += 256) PL[idx] = probs32[pdw + idx];
  }
  __syncthreads();
  const int wid = threadIdx.x>>6, lane = threadIdx.x&63;
  const uint32_t* vr = &VT[lane*147];
  for (int r=0; r<3; ++r) {
    const int nq = (r<2)?4:2;
    float o[4] = {0.f,0.f,0.f,0.f};
    const uint32_t* pr[4];
    for (int qi=0; qi<nq; ++qi) pr[qi] = &PL[(wid*10 + r*4 + qi)*144];
    const int jmax = nk>>1;
    #pragma unroll 2
    for (int j2=0; j2<jmax; j2+=2) {
      uint32_t v0 = vr[j2], v1 = vr[j2+1];
      for (int qi=0; qi<nq; ++qi) {
        uint32_t p0 = pr[qi][j2], p1 = pr[qi][j2+1];
        o[qi] = fdot2f(h2(v0), h2(p0), o[qi]);
        o[qi] = fdot2f(h2(v1), h2(p1), o[qi]);
      }
    }
    for (int qi=0; qi<nq; ++qi) {
      int ql = qg*40 + wid*10 + r*4 + qi;
      bool vq = (ci<7) || (ql>=32);
      if (vq) {
        int tq = (ql<32)?(32*ci+ql):(224+128*ci+ql-32);
        size_t mq = (size_t)(rowbase+tq);
        float hv = bf1(hres[mq*1024 + hh*64 + lane]);
        attn_out[mq*1024 + hh*64 + lane] = f2bf(o[qi] + hv);
      }
    }
  }
}

// ---------------------------------------------------------------------------
// Transpose + fp32->bf16 convert: dst[c][r] = bf16(src[r][c]).
// grid (C/32, R/32), block (32,8).
// ---------------------------------------------------------------------------
__global__ void transpose_k(const float* __restrict__ src, uint16_t* __restrict__ dst,
                            int R, int C) {
  __shared__ float t[32][33];
  int c0 = blockIdx.x*32, r0 = blockIdx.y*32;
  int tx = threadIdx.x, ty = threadIdx.y;
  #pragma unroll
  for (int i=0;i<4;i++) t[ty+8*i][tx] = src[(size_t)(r0+ty+8*i)*C + c0+tx];
  __syncthreads();
  #pragma unroll
  for (int i=0;i<4;i++) dst[(size_t)(c0+ty+8*i)*R + r0+tx] = f2bf(t[tx][ty+8*i]);
}

__global__ void catbias_k(const float* __restrict__ bq, const float* __restrict__ bk,
                          const float* __restrict__ bv, float* __restrict__ o) {
  int i = blockIdx.x*256 + threadIdx.x;
  o[i] = (i<1024) ? bq[i] : ((i<2048) ? bk[i-1024] : bv[i-2048]);
}

// ---------------------------------------------------------------------------
extern "C" void kernel_launch(void* const* d_in, const int* in_sizes, int n_in,
                              void* d_out, int out_size, void* d_ws, size_t ws_size,
                              hipStream_t stream) {
  const float* input  = (const float*)d_in[0];
  const float* lnin_s = (const float*)d_in[1];
  const float* lnin_b = (const float*)d_in[2];
  const float* Wq = (const float*)d_in[3];
  const float* bq = (const float*)d_in[4];
  const float* Wk = (const float*)d_in[5];
  const float* bk = (const float*)d_in[6];
  const float* Wv = (const float*)d_in[7];
  const float* bv = (const float*)d_in[8];
  const float* ln1_s = (const float*)d_in[9];
  const float* ln1_b = (const float*)d_in[10];
  const float* W1 = (const float*)d_in[11];
  const float* b1 = (const float*)d_in[12];
  const float* W2 = (const float*)d_in[13];
  const float* b2 = (const float*)d_in[14];
  const float* ln2_s = (const float*)d_in[15];
  const float* ln2_b = (const float*)d_in[16];
  // mask d_in[17] intentionally unused: Emformer mask is closed-form.

  char* ws = (char*)d_ws;
  uint16_t* wt_qkv = (uint16_t*)(ws + 0);         // bf16 [3072][1024]
  uint16_t* wt_w1  = (uint16_t*)(ws + 6291456);   // bf16 [4096][1024]
  uint16_t* wt_w2  = (uint16_t*)(ws + 14680064);  // bf16 [1024][4096]
  float*    bqkv   = (float*)   (ws + 23068672);  // f32  [3072]
  uint16_t* hbuf   = (uint16_t*)(ws + 23080960);  // bf16 [2560][1024]
  uint16_t* qkvb   = (uint16_t*)(ws + 28323840);  // bf16 [2560][3072]
  uint16_t* attnb  = (uint16_t*)(ws + 44052480);  // bf16 [2560][1024]
  uint16_t* zbuf   = (uint16_t*)(ws + 49295360);  // bf16 [2560][1024]
  uint16_t* probsb = (uint16_t*)(ws + 54538240);  // f16  [2*16*8*160][288]
  uint16_t* y1b    = hbuf;                        // bf16 [2560][4096] overlays hbuf+qkvb (dead)
  uint16_t* y2b    = probsb;                      // bf16 [2560][1024] overlays probs (dead)
  uint16_t* x1b    = (uint16_t*)(ws + 59781120);  // bf16 [2560][1024]
  // peak ws usage: 78,131,200 bytes

  dim3 tb(32,8);
  const uint16_t* xcur_bf = x1b;   // layer-1 input (bf16); layer 0 uses fp32 `input`
  for (int l=0; l<2; ++l) {
    transpose_k<<<dim3(32,32),  tb, 0, stream>>>(Wq + (size_t)l*1048576, wt_qkv,            1024, 1024);
    transpose_k<<<dim3(32,32),  tb, 0, stream>>>(Wk + (size_t)l*1048576, wt_qkv + 1048576,  1024, 1024);
    transpose_k<<<dim3(32,32),  tb, 0, stream>>>(Wv + (size_t)l*1048576, wt_qkv + 2097152,  1024, 1024);
    transpose_k<<<dim3(128,32), tb, 0, stream>>>(W1 + (size_t)l*4194304, wt_w1,             1024, 4096);
    transpose_k<<<dim3(32,128), tb, 0, stream>>>(W2 + (size_t)l*4194304, wt_w2,             4096, 1024);
    catbias_k<<<12,256,0,stream>>>(bq+l*1024, bk+l*1024, bv+l*1024, bqkv);

    if (l==0) ln_k<float,uint16_t>   <<<2496,256,0,stream>>>(input,   lnin_s+l*1024, lnin_b+l*1024, hbuf);
    else      ln_k<uint16_t,uint16_t><<<2496,256,0,stream>>>(xcur_bf, lnin_s+l*1024, lnin_b+l*1024, hbuf);
    gemm_bt<<<dim3(24,20),256,0,stream>>>(hbuf, wt_qkv, bqkv, nullptr, qkvb, 3072, 1024);
    attn_scores<<<1024,256,0,stream>>>((const uint32_t*)qkvb, probsb);
    attn_pv<<<1024,256,0,stream>>>((const uint32_t*)qkvb, (const uint32_t*)probsb, hbuf, attnb);
    ln_k<uint16_t,uint16_t><<<2496,256,0,stream>>>(attnb, ln1_s+l*1024, ln1_b+l*1024, zbuf);
    gemm_bt<<<dim3(32,20),256,0,stream>>>(zbuf, wt_w1, b1+l*4096, nullptr, y1b, 4096, 1024);
    gemm_bt<<<dim3(8,20),256,0,stream>>>(y1b, wt_w2, b2+l*1024, attnb, y2b, 1024, 4096);
    if (l==1) ln_k<uint16_t,float>   <<<2496,256,0,stream>>>(y2b, ln2_s+l*1024, ln2_b+l*1024, (float*)d_out);
    else      ln_k<uint16_t,uint16_t><<<2496,256,0,stream>>>(y2b, ln2_s+l*1024, ln2_b+l*1024, x1b);
  }
  (void)in_sizes; (void)n_in; (void)out_size; (void)ws_size;
}

// Round 4
// 605.736 us; speedup vs baseline: 1.2290x; 1.2290x over previous
//
#include <hip/hip_runtime.h>
#include <stdint.h>

typedef __attribute__((ext_vector_type(8))) short short8;
typedef __attribute__((ext_vector_type(4))) float f32x4;
typedef __attribute__((ext_vector_type(2))) _Float16 half2_t;

#define DEV __device__ __forceinline__

DEV float bits2f(uint32_t u){ union{uint32_t u;float f;}v; v.u=u; return v.f; }
DEV float bf_lo(uint32_t w){ return bits2f(w<<16); }
DEV float bf_hi(uint32_t w){ return bits2f(w & 0xffff0000u); }
DEV float bf1(uint16_t s){ return bits2f(((uint32_t)s)<<16); }
DEV uint16_t f2bf(float f){ union{float f;uint32_t u;}v; v.f=f; uint32_t u=v.u;
  return (uint16_t)((u + 0x7fffu + ((u>>16)&1u))>>16); }
DEV uint32_t pk16(float a, float b){ union{_Float16 h[2]; uint32_t u;}v;
  v.h[0]=(_Float16)a; v.h[1]=(_Float16)b; return v.u; }
DEV half2_t h2(uint32_t u){ union{uint32_t u; half2_t h;}v; v.u=u; return v.h; }

DEV float ldval(const float* p, size_t i){ return p[i]; }
DEV float ldval(const uint16_t* p, size_t i){ return bf1(p[i]); }
DEV void stval(float* p, size_t i, float v){ p[i]=v; }
DEV void stval(uint16_t* p, size_t i, float v){ p[i]=f2bf(v); }

DEV float fdot2f(half2_t a, half2_t b, float c){
#if __has_builtin(__builtin_amdgcn_fdot2)
  return __builtin_amdgcn_fdot2(a,b,c,false);
#else
  return c + (float)a[0]*(float)b[0] + (float)a[1]*(float)b[1];
#endif
}

DEV void async16(const void* g, void* l){
#if __has_builtin(__builtin_amdgcn_global_load_lds)
  __builtin_amdgcn_global_load_lds((const __attribute__((address_space(1))) void*)g,
                                   (__attribute__((address_space(3))) void*)l, 16, 0, 0);
#else
  int lane = threadIdx.x & 63;
  *(uint4*)((char*)l + lane*16) = *(const uint4*)((const char*)g);
#endif
}

// ---------------------------------------------------------------------------
// GEMM: C[M,N] = A[M,K] @ Bt[N,K]^T + bias[N].  M = gridDim.y*128.
// A, Bt, C bf16; bias fp32. m97 structure: 128x128 tile, BK=32.
// ---------------------------------------------------------------------------
__global__ __launch_bounds__(256) void gemm_bt(
    const uint16_t* __restrict__ A, const uint16_t* __restrict__ Bt,
    const float* __restrict__ bias, uint16_t* __restrict__ C, int N, int K) {
  __shared__ uint16_t sA[128*32];
  __shared__ uint16_t sB[128*32];
  const int m0 = blockIdx.y*128, n0 = blockIdx.x*128;
  const int tid = threadIdx.x, wid = tid>>6, lane = tid&63;
  const int wm = (wid>>1)*64, wn = (wid&1)*64;
  f32x4 acc[4][4];
  #pragma unroll
  for (int a=0;a<4;a++)
    #pragma unroll
    for (int b=0;b<4;b++) acc[a][b] = (f32x4){0.f,0.f,0.f,0.f};
  const int lrow = lane>>2, lcol = (lane&3)*8;

  for (int k0 = 0; k0 < K; k0 += 32) {
    __syncthreads();
    #pragma unroll
    for (int j = 0; j < 2; ++j) {
      int r0 = wid*32 + j*16;
      async16(A  + (size_t)(m0 + r0 + lrow)*K + k0 + lcol, &sA[r0*32]);
      async16(Bt + (size_t)(n0 + r0 + lrow)*K + k0 + lcol, &sB[r0*32]);
    }
    __syncthreads();
    short8 af[4], bfv[4];
    #pragma unroll
    for (int t=0;t<4;t++) {
      af[t]  = *(const short8*)&sA[(wm + t*16 + (lane&15))*32 + (lane>>4)*8];
      bfv[t] = *(const short8*)&sB[(wn + t*16 + (lane&15))*32 + (lane>>4)*8];
    }
    #pragma unroll
    for (int mt=0;mt<4;mt++)
      #pragma unroll
      for (int nt=0;nt<4;nt++)
        acc[mt][nt] = __builtin_amdgcn_mfma_f32_16x16x32_bf16(af[mt], bfv[nt], acc[mt][nt], 0,0,0);
  }
  const int cl = lane&15, rl = (lane>>4)*4;   // C/D: col=lane&15, row=(lane>>4)*4+reg
  #pragma unroll
  for (int nt=0;nt<4;nt++) {
    int n = n0 + wn + nt*16 + cl;
    float bv = bias ? bias[n] : 0.f;
    #pragma unroll
    for (int mt=0;mt<4;mt++) {
      #pragma unroll
      for (int r=0;r<4;r++) {
        int m = m0 + wm + mt*16 + rl + r;
        C[(size_t)m*N + n] = f2bf(acc[mt][nt][r] + bv);
      }
    }
  }
}

// Split-K variant: blockIdx.z selects K-chunk, writes fp32 partials (no bias).
__global__ __launch_bounds__(256) void gemm_bt_splitk(
    const uint16_t* __restrict__ A, const uint16_t* __restrict__ Bt,
    float* __restrict__ P, int N, int K, int kchunk) {
  __shared__ uint16_t sA[128*32];
  __shared__ uint16_t sB[128*32];
  const int m0 = blockIdx.y*128, n0 = blockIdx.x*128;
  const int kb = blockIdx.z*kchunk;
  const int tid = threadIdx.x, wid = tid>>6, lane = tid&63;
  const int wm = (wid>>1)*64, wn = (wid&1)*64;
  f32x4 acc[4][4];
  #pragma unroll
  for (int a=0;a<4;a++)
    #pragma unroll
    for (int b=0;b<4;b++) acc[a][b] = (f32x4){0.f,0.f,0.f,0.f};
  const int lrow = lane>>2, lcol = (lane&3)*8;

  for (int k0 = kb; k0 < kb+kchunk; k0 += 32) {
    __syncthreads();
    #pragma unroll
    for (int j = 0; j < 2; ++j) {
      int r0 = wid*32 + j*16;
      async16(A  + (size_t)(m0 + r0 + lrow)*K + k0 + lcol, &sA[r0*32]);
      async16(Bt + (size_t)(n0 + r0 + lrow)*K + k0 + lcol, &sB[r0*32]);
    }
    __syncthreads();
    short8 af[4], bfv[4];
    #pragma unroll
    for (int t=0;t<4;t++) {
      af[t]  = *(const short8*)&sA[(wm + t*16 + (lane&15))*32 + (lane>>4)*8];
      bfv[t] = *(const short8*)&sB[(wn + t*16 + (lane&15))*32 + (lane>>4)*8];
    }
    #pragma unroll
    for (int mt=0;mt<4;mt++)
      #pragma unroll
      for (int nt=0;nt<4;nt++)
        acc[mt][nt] = __builtin_amdgcn_mfma_f32_16x16x32_bf16(af[mt], bfv[nt], acc[mt][nt], 0,0,0);
  }
  float* Pz = P + (size_t)blockIdx.z*2560*N;
  const int cl = lane&15, rl = (lane>>4)*4;
  #pragma unroll
  for (int nt=0;nt<4;nt++) {
    int n = n0 + wn + nt*16 + cl;
    #pragma unroll
    for (int mt=0;mt<4;mt++) {
      #pragma unroll
      for (int r=0;r<4;r++) {
        int m = m0 + wm + mt*16 + rl + r;
        Pz[(size_t)m*N + n] = acc[mt][nt][r];
      }
    }
  }
}

// ---------------------------------------------------------------------------
// LayerNorm over D=1024, one block (256 thr) per row.
// ---------------------------------------------------------------------------
template<typename TI, typename TO>
__global__ __launch_bounds__(256) void ln_k(const TI* __restrict__ x,
    const float* __restrict__ sc, const float* __restrict__ bi,
    TO* __restrict__ out) {
  const int row = blockIdx.x, tid = threadIdx.x;
  const size_t base = (size_t)row*1024 + tid*4;
  float v0=ldval(x,base), v1=ldval(x,base+1), v2=ldval(x,base+2), v3=ldval(x,base+3);
  float s = v0+v1+v2+v3;
  float sq = v0*v0+v1*v1+v2*v2+v3*v3;
  #pragma unroll
  for (int off=32; off; off>>=1){ s += __shfl_xor(s,off); sq += __shfl_xor(sq,off); }
  __shared__ float red[8];
  int wid=tid>>6, lane=tid&63;
  if (lane==0){ red[wid]=s; red[4+wid]=sq; }
  __syncthreads();
  s = red[0]+red[1]+red[2]+red[3]; sq = red[4]+red[5]+red[6]+red[7];
  float mean = s*(1.f/1024.f);
  float inv  = rsqrtf(sq*(1.f/1024.f) - mean*mean + 1e-5f);
  int c = tid*4;
  stval(out, base,   (v0-mean)*inv*sc[c]   + bi[c]);
  stval(out, base+1, (v1-mean)*inv*sc[c+1] + bi[c+1]);
  stval(out, base+2, (v2-mean)*inv*sc[c+2] + bi[c+2]);
  stval(out, base+3, (v3-mean)*inv*sc[c+3] + bi[c+3]);
}

// Fused: y = P[0][row]+P[1][row] + b2 + resid(bf16); out = LN(y).
template<typename TO>
__global__ __launch_bounds__(256) void ln2_fused(const float* __restrict__ P,
    const float* __restrict__ b2, const uint16_t* __restrict__ resid,
    const float* __restrict__ sc, const float* __restrict__ bi,
    TO* __restrict__ out) {
  const int row = blockIdx.x, tid = threadIdx.x;
  const size_t base = (size_t)row*1024 + tid*4;
  float4 p0 = *(const float4*)(P + base);
  float4 p1 = *(const float4*)(P + (size_t)2560*1024 + base);
  int c = tid*4;
  float v0 = p0.x+p1.x+b2[c]  +bf1(resid[base]);
  float v1 = p0.y+p1.y+b2[c+1]+bf1(resid[base+1]);
  float v2 = p0.z+p1.z+b2[c+2]+bf1(resid[base+2]);
  float v3 = p0.w+p1.w+b2[c+3]+bf1(resid[base+3]);
  float s = v0+v1+v2+v3;
  float sq = v0*v0+v1*v1+v2*v2+v3*v3;
  #pragma unroll
  for (int off=32; off; off>>=1){ s += __shfl_xor(s,off); sq += __shfl_xor(sq,off); }
  __shared__ float red[8];
  int wid=tid>>6, lane=tid&63;
  if (lane==0){ red[wid]=s; red[4+wid]=sq; }
  __syncthreads();
  s = red[0]+red[1]+red[2]+red[3]; sq = red[4]+red[5]+red[6]+red[7];
  float mean = s*(1.f/1024.f);
  float inv  = rsqrtf(sq*(1.f/1024.f) - mean*mean + 1e-5f);
  stval(out, base,   (v0-mean)*inv*sc[c]   + bi[c]);
  stval(out, base+1, (v1-mean)*inv*sc[c+1] + bi[c+1]);
  stval(out, base+2, (v2-mean)*inv*sc[c+2] + bi[c+2]);
  stval(out, base+3, (v3-mean)*inv*sc[c+3] + bi[c+3]);
}

// ---------------------------------------------------------------------------
// Emformer attention, closed-form mask (see round-0 derivation).
// ---------------------------------------------------------------------------
__global__ __launch_bounds__(256) void attn_scores(
    const uint32_t* __restrict__ qkv32, uint16_t* __restrict__ probs) {
  const int blk = blockIdx.x;
  const int qg = blk & 3, ci = (blk>>2)&7, hh = (blk>>5)&15, bb = blk>>9;
  const int sum_cnt = (ci<7)?32:0;
  const int bstart = (ci>=1)?128*(ci-1):0;
  const int bend = (ci==7)?1024:128*(ci+1);
  const int nk = sum_cnt + (bend - bstart);          // 160 / 288 / 256
  const int rowbase = bb*1248;
  __shared__ uint32_t K2[288*33];
  for (int idx = threadIdx.x; idx < nk*32; idx += 256) {
    int j = idx>>5, d2 = idx&31;
    int tk = (j < sum_cnt) ? (32*ci + j) : (224 + bstart + (j - sum_cnt));
    uint32_t u = qkv32[(size_t)(rowbase+tk)*1536 + 512 + hh*32 + d2];
    K2[j*33+d2] = pk16(bf_lo(u), bf_hi(u));
  }
  __syncthreads();
  const int wid = threadIdx.x>>6, lane = threadIdx.x&63;
  const int qbase = qg*40 + wid*10;
  const size_t pbase = (size_t)((bb*16+hh)*8 + ci)*160;

  for (int pp=0; pp<10; pp+=2) {
    int ql[2] = {qbase+pp, qbase+pp+1};
    half2_t qh0[32], qh1[32];
    {
      int tq0 = (ql[0]<32)?(32*ci+ql[0]):(224+128*ci+ql[0]-32);
      int tq1 = (ql[1]<32)?(32*ci+ql[1]):(224+128*ci+ql[1]-32);
      const uint32_t* p0 = qkv32 + (size_t)(rowbase+tq0)*1536 + hh*32;
      const uint32_t* p1 = qkv32 + (size_t)(rowbase+tq1)*1536 + hh*32;
      #pragma unroll
      for (int d2=0; d2<32; ++d2) {
        uint32_t u0=p0[d2]; qh0[d2]=h2(pk16(bf_lo(u0),bf_hi(u0)));
        uint32_t u1=p1[d2]; qh1[d2]=h2(pk16(bf_lo(u1),bf_hi(u1)));
      }
    }
    float sc0[5], sc1[5];
    #pragma unroll
    for (int g=0; g<5; ++g) { sc0[g]=-1e30f; sc1[g]=-1e30f; }
    #pragma unroll
    for (int g=0; g<5; ++g) {
      if (g*64 < nk) {
        int jl = g*64 + lane; bool ok = jl < nk; int jc = ok ? jl : 0;
        const uint32_t* kr = &K2[jc*33];
        float a0=0.f, a1=0.f;
        #pragma unroll
        for (int d2=0; d2<32; ++d2) {
          half2_t kh = h2(kr[d2]);
          a0 = fdot2f(kh, qh0[d2], a0);
          a1 = fdot2f(kh, qh1[d2], a1);
        }
        if (ok) { sc0[g] = a0*0.125f; sc1[g] = a1*0.125f; }
      }
    }
    #pragma unroll
    for (int qi=0; qi<2; ++qi) {
      float* sc = qi ? sc1 : sc0;
      float mx = -1e30f;
      #pragma unroll
      for (int g=0; g<5; ++g) mx = fmaxf(mx, sc[g]);
      #pragma unroll
      for (int off=32; off; off>>=1) mx = fmaxf(mx, __shfl_xor(mx,off));
      float sum = 0.f;
      #pragma unroll
      for (int g=0; g<5; ++g) { float p = __expf(sc[g]-mx); sc[g]=p; sum+=p; }
      #pragma unroll
      for (int off=32; off; off>>=1) sum += __shfl_xor(sum,off);
      float inv = 1.f/sum;
      bool vq = (ci<7) || (ql[qi]>=32);
      if (vq) {
        uint16_t* prow = probs + (pbase + ql[qi])*288;
        #pragma unroll
        for (int g=0; g<5; ++g) {
          int jl = g*64+lane;
          if (jl < nk) { union{_Float16 h; uint16_t u;}cv; cv.h=(_Float16)(sc[g]*inv); prow[jl]=cv.u; }
        }
      }
    }
  }
}

__global__ __launch_bounds__(256) void attn_pv(
    const uint32_t* __restrict__ qkv32, const uint32_t* __restrict__ probs32,
    const uint16_t* __restrict__ hres, uint16_t* __restrict__ attn_out) {
  const int blk = blockIdx.x;
  const int qg = blk & 3, ci = (blk>>2)&7, hh = (blk>>5)&15, bb = blk>>9;
  const int sum_cnt = (ci<7)?32:0;
  const int bstart = (ci>=1)?128*(ci-1):0;
  const int bend = (ci==7)?1024:128*(ci+1);
  const int nk = sum_cnt + (bend - bstart);
  const int rowbase = bb*1248;
  __shared__ uint32_t VT[64*147];
  __shared__ uint32_t PL[40*144];
  for (int idx = threadIdx.x; idx < nk*32; idx += 256) {
    int j = idx>>5, d2 = idx&31;
    int tk = (j < sum_cnt) ? (32*ci + j) : (224 + bstart + (j - sum_cnt));
    uint32_t u = qkv32[(size_t)(rowbase+tk)*1536 + 1024 + hh*32 + d2];
    uint16_t* vt16 = (uint16_t*)VT;
    union{_Float16 h; uint16_t u;}c0, c1;
    c0.h = (_Float16)bf_lo(u); c1.h = (_Float16)bf_hi(u);
    vt16[(2*d2)*294 + j]   = c0.u;
    vt16[(2*d2+1)*294 + j] = c1.u;
  }
  {
    const size_t pdw = ((size_t)((bb*16+hh)*8 + ci)*160 + qg*40)*144;
    for (int idx = threadIdx.x; idx < 40*144; idx += 256) PL[idx] = probs32[pdw + idx];
  }
  __syncthreads();
  const int wid = threadIdx.x>>6, lane = threadIdx.x&63;
  const uint32_t* vr = &VT[lane*147];
  for (int r=0; r<3; ++r) {
    const int nq = (r<2)?4:2;
    float o[4] = {0.f,0.f,0.f,0.f};
    const uint32_t* pr[4];
    for (int qi=0; qi<nq; ++qi) pr[qi] = &PL[(wid*10 + r*4 + qi)*144];
    const int jmax = nk>>1;
    #pragma unroll 2
    for (int j2=0; j2<jmax; j2+=2) {
      uint32_t v0 = vr[j2], v1 = vr[j2+1];
      for (int qi=0; qi<nq; ++qi) {
        uint32_t p0 = pr[qi][j2], p1 = pr[qi][j2+1];
        o[qi] = fdot2f(h2(v0), h2(p0), o[qi]);
        o[qi] = fdot2f(h2(v1), h2(p1), o[qi]);
      }
    }
    for (int qi=0; qi<nq; ++qi) {
      int ql = qg*40 + wid*10 + r*4 + qi;
      bool vq = (ci<7) || (ql>=32);
      if (vq) {
        int tq = (ql<32)?(32*ci+ql):(224+128*ci+ql-32);
        size_t mq = (size_t)(rowbase+tq);
        float hv = bf1(hres[mq*1024 + hh*64 + lane]);
        attn_out[mq*1024 + hh*64 + lane] = f2bf(o[qi] + hv);
      }
    }
  }
}

// ---------------------------------------------------------------------------
// One-dispatch weight prep for a layer: transposes Wq,Wk,Wv ([1024][1024]),
// W1 ([1024][4096] -> [4096][1024]), W2 ([4096][1024] -> [1024][4096]) to
// bf16 [N][K], plus QKV bias concat. Grid 11276 x (32,8).
// ---------------------------------------------------------------------------
__global__ void prep_k(const float* __restrict__ Wq, const float* __restrict__ Wk,
                       const float* __restrict__ Wv, const float* __restrict__ W1,
                       const float* __restrict__ W2, const float* __restrict__ bq,
                       const float* __restrict__ bk, const float* __restrict__ bv,
                       uint16_t* __restrict__ wt_qkv, uint16_t* __restrict__ wt_w1,
                       uint16_t* __restrict__ wt_w2, float* __restrict__ bqkv) {
  __shared__ float t[32][33];
  const int blk = blockIdx.x;
  const int tx = threadIdx.x, ty = threadIdx.y;
  if (blk >= 11264) {                      // bias concat: 12 blocks x 256 thr
    int i = (blk-11264)*256 + ty*32 + tx;
    bqkv[i] = (i<1024) ? bq[i] : ((i<2048) ? bk[i-1024] : bv[i-2048]);
    return;
  }
  const float* src; uint16_t* dst; int R, C, c0, r0;
  if (blk < 3072) {
    int w = blk>>10, tt = blk&1023;
    src = (w==0)?Wq:((w==1)?Wk:Wv); dst = wt_qkv + (size_t)w*1048576;
    R = 1024; C = 1024; c0 = (tt&31)*32; r0 = (tt>>5)*32;
  } else if (blk < 7168) {
    int tt = blk-3072;
    src = W1; dst = wt_w1; R = 1024; C = 4096;
    c0 = (tt&127)*32; r0 = (tt>>7)*32;
  } else {
    int tt = blk-7168;
    src = W2; dst = wt_w2; R = 4096; C = 1024;
    c0 = (tt&31)*32; r0 = (tt>>5)*32;
  }
  #pragma unroll
  for (int i=0;i<4;i++) t[ty+8*i][tx] = src[(size_t)(r0+ty+8*i)*C + c0+tx];
  __syncthreads();
  #pragma unroll
  for (int i=0;i<4;i++) dst[(size_t)(c0+ty+8*i)*R + r0+tx] = f2bf(t[tx][ty+8*i]);
}

// ---------------------------------------------------------------------------
extern "C" void kernel_launch(void* const* d_in, const int* in_sizes, int n_in,
                              void* d_out, int out_size, void* d_ws, size_t ws_size,
                              hipStream_t stream) {
  const float* input  = (const float*)d_in[0];
  const float* lnin_s = (const float*)d_in[1];
  const float* lnin_b = (const float*)d_in[2];
  const float* Wq = (const float*)d_in[3];
  const float* bq = (const float*)d_in[4];
  const float* Wk = (const float*)d_in[5];
  const float* bk = (const float*)d_in[6];
  const float* Wv = (const float*)d_in[7];
  const float* bv = (const float*)d_in[8];
  const float* ln1_s = (const float*)d_in[9];
  const float* ln1_b = (const float*)d_in[10];
  const float* W1 = (const float*)d_in[11];
  const float* b1 = (const float*)d_in[12];
  const float* W2 = (const float*)d_in[13];
  const float* b2 = (const float*)d_in[14];
  const float* ln2_s = (const float*)d_in[15];
  const float* ln2_b = (const float*)d_in[16];
  // mask d_in[17] unused: Emformer mask is closed-form.

  char* ws = (char*)d_ws;
  uint16_t* wt_qkv = (uint16_t*)(ws + 0);         // bf16 [3072][1024]
  uint16_t* wt_w1  = (uint16_t*)(ws + 6291456);   // bf16 [4096][1024]
  uint16_t* wt_w2  = (uint16_t*)(ws + 14680064);  // bf16 [1024][4096]
  float*    bqkv   = (float*)   (ws + 23068672);  // f32  [3072]
  uint16_t* hbuf   = (uint16_t*)(ws + 23080960);  // bf16 [2560][1024]
  uint16_t* qkvb   = (uint16_t*)(ws + 28323840);  // bf16 [2560][3072]
  uint16_t* attnb  = (uint16_t*)(ws + 44052480);  // bf16 [2560][1024]
  uint16_t* zbuf   = (uint16_t*)(ws + 49295360);  // bf16 [2560][1024]
  uint16_t* probsb = (uint16_t*)(ws + 54538240);  // f16 [40960][288] (23.6 MB)
  float*    pbuf   = (float*)   (ws + 54538240);  // fp32 [2][2560][1024] overlays probs (dead)
  uint16_t* y1b    = hbuf;                        // bf16 [2560][4096] overlays hbuf+qkvb (dead)
  uint16_t* x1b    = zbuf;                        // layer-0 output overlays zbuf (dead at ln2;
                                                  // consumed by layer-1 ln_k before zbuf rewrite).
                                                  // NOTE round-3 bug: x1b previously overlapped pbuf -> race.
  // peak ws usage: 78,131,200 bytes

  const uint16_t* xcur_bf = x1b;
  for (int l=0; l<2; ++l) {
    prep_k<<<11276, dim3(32,8), 0, stream>>>(Wq+(size_t)l*1048576, Wk+(size_t)l*1048576,
        Wv+(size_t)l*1048576, W1+(size_t)l*4194304, W2+(size_t)l*4194304,
        bq+l*1024, bk+l*1024, bv+l*1024, wt_qkv, wt_w1, wt_w2, bqkv);

    if (l==0) ln_k<float,uint16_t>   <<<2496,256,0,stream>>>(input,   lnin_s+l*1024, lnin_b+l*1024, hbuf);
    else      ln_k<uint16_t,uint16_t><<<2496,256,0,stream>>>(xcur_bf, lnin_s+l*1024, lnin_b+l*1024, hbuf);
    gemm_bt<<<dim3(24,20),256,0,stream>>>(hbuf, wt_qkv, bqkv, qkvb, 3072, 1024);
    attn_scores<<<1024,256,0,stream>>>((const uint32_t*)qkvb, probsb);
    attn_pv<<<1024,256,0,stream>>>((const uint32_t*)qkvb, (const uint32_t*)probsb, hbuf, attnb);
    ln_k<uint16_t,uint16_t><<<2496,256,0,stream>>>(attnb, ln1_s+l*1024, ln1_b+l*1024, zbuf);
    gemm_bt<<<dim3(32,20),256,0,stream>>>(zbuf, wt_w1, b1+l*4096, y1b, 4096, 1024);
    gemm_bt_splitk<<<dim3(8,20,2),256,0,stream>>>(y1b, wt_w2, pbuf, 1024, 4096, 2048);
    if (l==1) ln2_fused<float>   <<<2496,256,0,stream>>>(pbuf, b2+l*1024, attnb, ln2_s+l*1024, ln2_b+l*1024, (float*)d_out);
    else      ln2_fused<uint16_t><<<2496,256,0,stream>>>(pbuf, b2+l*1024, attnb, ln2_s+l*1024, ln2_b+l*1024, x1b);
  }
  (void)in_sizes; (void)n_in; (void)out_size; (void)ws_size;
}

// Round 5
// 595.395 us; speedup vs baseline: 1.2503x; 1.0174x over previous
//
#include <hip/hip_runtime.h>
#include <stdint.h>

typedef __attribute__((ext_vector_type(8))) short short8;
typedef __attribute__((ext_vector_type(4))) float f32x4;
typedef __attribute__((ext_vector_type(2))) _Float16 half2_t;

#define DEV __device__ __forceinline__

DEV float bits2f(uint32_t u){ union{uint32_t u;float f;}v; v.u=u; return v.f; }
DEV float bf_lo(uint32_t w){ return bits2f(w<<16); }
DEV float bf_hi(uint32_t w){ return bits2f(w & 0xffff0000u); }
DEV float bf1(uint16_t s){ return bits2f(((uint32_t)s)<<16); }
DEV uint16_t f2bf(float f){ union{float f;uint32_t u;}v; v.f=f; uint32_t u=v.u;
  return (uint16_t)((u + 0x7fffu + ((u>>16)&1u))>>16); }
DEV uint32_t pk16(float a, float b){ union{_Float16 h[2]; uint32_t u;}v;
  v.h[0]=(_Float16)a; v.h[1]=(_Float16)b; return v.u; }
DEV half2_t h2(uint32_t u){ union{uint32_t u; half2_t h;}v; v.u=u; return v.h; }

DEV float ldval(const float* p, size_t i){ return p[i]; }
DEV float ldval(const uint16_t* p, size_t i){ return bf1(p[i]); }
DEV void stval(float* p, size_t i, float v){ p[i]=v; }
DEV void stval(uint16_t* p, size_t i, float v){ p[i]=f2bf(v); }

DEV float fdot2f(half2_t a, half2_t b, float c){
#if __has_builtin(__builtin_amdgcn_fdot2)
  return __builtin_amdgcn_fdot2(a,b,c,false);
#else
  return c + (float)a[0]*(float)b[0] + (float)a[1]*(float)b[1];
#endif
}

DEV void async16(const void* g, void* l){
#if __has_builtin(__builtin_amdgcn_global_load_lds)
  __builtin_amdgcn_global_load_lds((const __attribute__((address_space(1))) void*)g,
                                   (__attribute__((address_space(3))) void*)l, 16, 0, 0);
#else
  int lane = threadIdx.x & 63;
  *(uint4*)((char*)l + lane*16) = *(const uint4*)((const char*)g);
#endif
}

// ---------------------------------------------------------------------------
// GEMM: C[M,N] = A[M,K] @ Bt[N,K]^T (+bias). Tile TM x 128, 4 waves of
// (TM/2) x 64. TM=64 doubles grid vs round-4 (latency-bound: occupancy wins).
// SPLIT: blockIdx.z K-chunking, fp32 partials at z*2560*N, no bias.
// ---------------------------------------------------------------------------
template<int TM, bool SPLIT>
__global__ __launch_bounds__(256) void gemm_t(
    const uint16_t* __restrict__ A, const uint16_t* __restrict__ Bt,
    const float* __restrict__ bias, void* __restrict__ Cout,
    int N, int K, int kchunk) {
  __shared__ uint16_t sA[TM*32];
  __shared__ uint16_t sB[128*32];
  const int m0 = blockIdx.y*TM, n0 = blockIdx.x*128;
  const int kb = SPLIT ? blockIdx.z*kchunk : 0;
  const int kend = SPLIT ? kb + kchunk : K;
  const int tid = threadIdx.x, wid = tid>>6, lane = tid&63;
  constexpr int WM = TM/2;           // rows per wave
  constexpr int MT = WM/16;          // m-frags per wave (2 or 4)
  const int wm = (wid&1)*WM, wn = (wid>>1)*64;
  f32x4 acc[MT][4];
  #pragma unroll
  for (int a=0;a<MT;a++)
    #pragma unroll
    for (int b=0;b<4;b++) acc[a][b] = (f32x4){0.f,0.f,0.f,0.f};
  const int lrow = lane>>2, lcol = (lane&3)*8;

  for (int k0 = kb; k0 < kend; k0 += 32) {
    __syncthreads();
    #pragma unroll
    for (int j = 0; j < TM/64; ++j) {
      int r0 = wid*(TM/4) + j*16;
      async16(A + (size_t)(m0 + r0 + lrow)*K + k0 + lcol, &sA[r0*32]);
    }
    #pragma unroll
    for (int j = 0; j < 2; ++j) {
      int r0 = wid*32 + j*16;
      async16(Bt + (size_t)(n0 + r0 + lrow)*K + k0 + lcol, &sB[r0*32]);
    }
    __syncthreads();
    short8 af[MT], bfv[4];
    #pragma unroll
    for (int t=0;t<MT;t++) af[t] = *(const short8*)&sA[(wm + t*16 + (lane&15))*32 + (lane>>4)*8];
    #pragma unroll
    for (int t=0;t<4;t++)  bfv[t] = *(const short8*)&sB[(wn + t*16 + (lane&15))*32 + (lane>>4)*8];
    #pragma unroll
    for (int mt=0;mt<MT;mt++)
      #pragma unroll
      for (int nt=0;nt<4;nt++)
        acc[mt][nt] = __builtin_amdgcn_mfma_f32_16x16x32_bf16(af[mt], bfv[nt], acc[mt][nt], 0,0,0);
  }
  const int cl = lane&15, rl = (lane>>4)*4;   // C/D: col=lane&15, row=(lane>>4)*4+reg
  if (SPLIT) {
    float* Pz = (float*)Cout + (size_t)blockIdx.z*2560*N;
    #pragma unroll
    for (int nt=0;nt<4;nt++) {
      int n = n0 + wn + nt*16 + cl;
      #pragma unroll
      for (int mt=0;mt<MT;mt++)
        #pragma unroll
        for (int r=0;r<4;r++)
          Pz[(size_t)(m0 + wm + mt*16 + rl + r)*N + n] = acc[mt][nt][r];
    }
  } else {
    uint16_t* C = (uint16_t*)Cout;
    #pragma unroll
    for (int nt=0;nt<4;nt++) {
      int n = n0 + wn + nt*16 + cl;
      float bv = bias ? bias[n] : 0.f;
      #pragma unroll
      for (int mt=0;mt<MT;mt++)
        #pragma unroll
        for (int r=0;r<4;r++)
          C[(size_t)(m0 + wm + mt*16 + rl + r)*N + n] = f2bf(acc[mt][nt][r] + bv);
    }
  }
}

// ---------------------------------------------------------------------------
// LayerNorm over D=1024, one block (256 thr) per row.
// ---------------------------------------------------------------------------
template<typename TI, typename TO>
__global__ __launch_bounds__(256) void ln_k(const TI* __restrict__ x,
    const float* __restrict__ sc, const float* __restrict__ bi,
    TO* __restrict__ out) {
  const int row = blockIdx.x, tid = threadIdx.x;
  const size_t base = (size_t)row*1024 + tid*4;
  float v0=ldval(x,base), v1=ldval(x,base+1), v2=ldval(x,base+2), v3=ldval(x,base+3);
  float s = v0+v1+v2+v3;
  float sq = v0*v0+v1*v1+v2*v2+v3*v3;
  #pragma unroll
  for (int off=32; off; off>>=1){ s += __shfl_xor(s,off); sq += __shfl_xor(sq,off); }
  __shared__ float red[8];
  int wid=tid>>6, lane=tid&63;
  if (lane==0){ red[wid]=s; red[4+wid]=sq; }
  __syncthreads();
  s = red[0]+red[1]+red[2]+red[3]; sq = red[4]+red[5]+red[6]+red[7];
  float mean = s*(1.f/1024.f);
  float inv  = rsqrtf(sq*(1.f/1024.f) - mean*mean + 1e-5f);
  int c = tid*4;
  stval(out, base,   (v0-mean)*inv*sc[c]   + bi[c]);
  stval(out, base+1, (v1-mean)*inv*sc[c+1] + bi[c+1]);
  stval(out, base+2, (v2-mean)*inv*sc[c+2] + bi[c+2]);
  stval(out, base+3, (v3-mean)*inv*sc[c+3] + bi[c+3]);
}

// Fused: y = P[0][row]+P[1][row] + b2 + resid(bf16); out = LN(y).
template<typename TO>
__global__ __launch_bounds__(256) void ln2_fused(const float* __restrict__ P,
    const float* __restrict__ b2, const uint16_t* __restrict__ resid,
    const float* __restrict__ sc, const float* __restrict__ bi,
    TO* __restrict__ out) {
  const int row = blockIdx.x, tid = threadIdx.x;
  const size_t base = (size_t)row*1024 + tid*4;
  float4 p0 = *(const float4*)(P + base);
  float4 p1 = *(const float4*)(P + (size_t)2560*1024 + base);
  int c = tid*4;
  float v0 = p0.x+p1.x+b2[c]  +bf1(resid[base]);
  float v1 = p0.y+p1.y+b2[c+1]+bf1(resid[base+1]);
  float v2 = p0.z+p1.z+b2[c+2]+bf1(resid[base+2]);
  float v3 = p0.w+p1.w+b2[c+3]+bf1(resid[base+3]);
  float s = v0+v1+v2+v3;
  float sq = v0*v0+v1*v1+v2*v2+v3*v3;
  #pragma unroll
  for (int off=32; off; off>>=1){ s += __shfl_xor(s,off); sq += __shfl_xor(sq,off); }
  __shared__ float red[8];
  int wid=tid>>6, lane=tid&63;
  if (lane==0){ red[wid]=s; red[4+wid]=sq; }
  __syncthreads();
  s = red[0]+red[1]+red[2]+red[3]; sq = red[4]+red[5]+red[6]+red[7];
  float mean = s*(1.f/1024.f);
  float inv  = rsqrtf(sq*(1.f/1024.f) - mean*mean + 1e-5f);
  stval(out, base,   (v0-mean)*inv*sc[c]   + bi[c]);
  stval(out, base+1, (v1-mean)*inv*sc[c+1] + bi[c+1]);
  stval(out, base+2, (v2-mean)*inv*sc[c+2] + bi[c+2]);
  stval(out, base+3, (v3-mean)*inv*sc[c+3] + bi[c+3]);
}

// ---------------------------------------------------------------------------
// Fused Emformer attention (scores + softmax + PV), closed-form mask.
// Probs live in LDS; V^T reuses K2's LDS region after a barrier.
// Block = (bb,hh,ci,qg): 40 queries. LDS 61,696 B -> 2 blocks/CU.
// ---------------------------------------------------------------------------
__global__ __launch_bounds__(256) void attn_fused(
    const uint32_t* __restrict__ qkv32, const uint16_t* __restrict__ hres,
    uint16_t* __restrict__ attn_out) {
  const int blk = blockIdx.x;
  const int qg = blk & 3, ci = (blk>>2)&7, hh = (blk>>5)&15, bb = blk>>9;
  const int sum_cnt = (ci<7)?32:0;
  const int bstart = (ci>=1)?128*(ci-1):0;
  const int bend = (ci==7)?1024:128*(ci+1);
  const int nk = sum_cnt + (bend - bstart);          // 160 / 256 / 288
  const int rowbase = bb*1248;
  __shared__ uint32_t smem[288*33 + 40*148];         // K2/VT region + PL
  uint32_t* K2 = smem;                               // keys f16-pairs [key][33]
  uint32_t* PL = smem + 288*33;                      // probs f16 [40][stride 148 dw]
  uint16_t* PL16 = (uint16_t*)PL;

  // ---- stage K ----
  for (int idx = threadIdx.x; idx < nk*32; idx += 256) {
    int j = idx>>5, d2 = idx&31;
    int tk = (j < sum_cnt) ? (32*ci + j) : (224 + bstart + (j - sum_cnt));
    uint32_t u = qkv32[(size_t)(rowbase+tk)*1536 + 512 + hh*32 + d2];
    K2[j*33+d2] = pk16(bf_lo(u), bf_hi(u));
  }
  __syncthreads();

  const int wid = threadIdx.x>>6, lane = threadIdx.x&63;
  const int qbase = qg*40 + wid*10;

  // ---- scores + softmax -> PL ----
  for (int pp=0; pp<10; pp+=2) {
    int ql[2] = {qbase+pp, qbase+pp+1};
    half2_t qh0[32], qh1[32];
    {
      int tq0 = (ql[0]<32)?(32*ci+ql[0]):(224+128*ci+ql[0]-32);
      int tq1 = (ql[1]<32)?(32*ci+ql[1]):(224+128*ci+ql[1]-32);
      const uint32_t* p0 = qkv32 + (size_t)(rowbase+tq0)*1536 + hh*32;
      const uint32_t* p1 = qkv32 + (size_t)(rowbase+tq1)*1536 + hh*32;
      #pragma unroll
      for (int d2=0; d2<32; ++d2) {
        uint32_t u0=p0[d2]; qh0[d2]=h2(pk16(bf_lo(u0),bf_hi(u0)));
        uint32_t u1=p1[d2]; qh1[d2]=h2(pk16(bf_lo(u1),bf_hi(u1)));
      }
    }
    float sc0[5], sc1[5];
    #pragma unroll
    for (int g=0; g<5; ++g) { sc0[g]=-1e30f; sc1[g]=-1e30f; }
    #pragma unroll
    for (int g=0; g<5; ++g) {
      if (g*64 < nk) {
        int jl = g*64 + lane; bool ok = jl < nk; int jc = ok ? jl : 0;
        const uint32_t* kr = &K2[jc*33];
        float a0=0.f, a1=0.f;
        #pragma unroll
        for (int d2=0; d2<32; ++d2) {
          half2_t kh = h2(kr[d2]);
          a0 = fdot2f(kh, qh0[d2], a0);
          a1 = fdot2f(kh, qh1[d2], a1);
        }
        if (ok) { sc0[g] = a0*0.125f; sc1[g] = a1*0.125f; }
      }
    }
    #pragma unroll
    for (int qi=0; qi<2; ++qi) {
      float* sc = qi ? sc1 : sc0;
      float mx = -1e30f;
      #pragma unroll
      for (int g=0; g<5; ++g) mx = fmaxf(mx, sc[g]);
      #pragma unroll
      for (int off=32; off; off>>=1) mx = fmaxf(mx, __shfl_xor(mx,off));
      float sum = 0.f;
      #pragma unroll
      for (int g=0; g<5; ++g) { float p = __expf(sc[g]-mx); sc[g]=p; sum+=p; }
      #pragma unroll
      for (int off=32; off; off>>=1) sum += __shfl_xor(sum,off);
      float inv = 1.f/sum;
      int qlocal = wid*10 + pp + qi;
      #pragma unroll
      for (int g=0; g<5; ++g) {
        int jl = g*64+lane;
        if (jl < nk) {
          union{_Float16 h; uint16_t u;}cv; cv.h=(_Float16)(sc[g]*inv);
          PL16[qlocal*296 + jl] = cv.u;
        }
      }
    }
  }
  __syncthreads();

  // ---- stage V^T into K2's region (stride 147 dw, odd -> conflict-free) ----
  uint16_t* vt16 = (uint16_t*)K2;
  for (int idx = threadIdx.x; idx < nk*32; idx += 256) {
    int j = idx>>5, d2 = idx&31;
    int tk = (j < sum_cnt) ? (32*ci + j) : (224 + bstart + (j - sum_cnt));
    uint32_t u = qkv32[(size_t)(rowbase+tk)*1536 + 1024 + hh*32 + d2];
    union{_Float16 h; uint16_t u;}c0, c1;
    c0.h = (_Float16)bf_lo(u); c1.h = (_Float16)bf_hi(u);
    vt16[(2*d2)*294 + j]   = c0.u;
    vt16[(2*d2+1)*294 + j] = c1.u;
  }
  __syncthreads();

  // ---- PV + residual ----
  const uint32_t* vr = &K2[lane*147];
  for (int r=0; r<3; ++r) {
    const int nq = (r<2)?4:2;
    float o[4] = {0.f,0.f,0.f,0.f};
    const uint32_t* pr[4];
    for (int qi=0; qi<nq; ++qi) pr[qi] = &PL[(wid*10 + r*4 + qi)*148];
    const int jmax = nk>>1;
    #pragma unroll 2
    for (int j2=0; j2<jmax; j2+=2) {
      uint32_t v0 = vr[j2], v1 = vr[j2+1];
      for (int qi=0; qi<nq; ++qi) {
        uint32_t p0 = pr[qi][j2], p1 = pr[qi][j2+1];
        o[qi] = fdot2f(h2(v0), h2(p0), o[qi]);
        o[qi] = fdot2f(h2(v1), h2(p1), o[qi]);
      }
    }
    for (int qi=0; qi<nq; ++qi) {
      int ql = qg*40 + wid*10 + r*4 + qi;
      bool vq = (ci<7) || (ql>=32);
      if (vq) {
        int tq = (ql<32)?(32*ci+ql):(224+128*ci+ql-32);
        size_t mq = (size_t)(rowbase+tq);
        float hv = bf1(hres[mq*1024 + hh*64 + lane]);
        attn_out[mq*1024 + hh*64 + lane] = f2bf(o[qi] + hv);
      }
    }
  }
}

// ---------------------------------------------------------------------------
// One-dispatch weight prep: transpose Wq,Wk,Wv,W1,W2 to bf16 [N][K] + bias cat.
// ---------------------------------------------------------------------------
__global__ void prep_k(const float* __restrict__ Wq, const float* __restrict__ Wk,
                       const float* __restrict__ Wv, const float* __restrict__ W1,
                       const float* __restrict__ W2, const float* __restrict__ bq,
                       const float* __restrict__ bk, const float* __restrict__ bv,
                       uint16_t* __restrict__ wt_qkv, uint16_t* __restrict__ wt_w1,
                       uint16_t* __restrict__ wt_w2, float* __restrict__ bqkv) {
  __shared__ float t[32][33];
  const int blk = blockIdx.x;
  const int tx = threadIdx.x, ty = threadIdx.y;
  if (blk >= 11264) {
    int i = (blk-11264)*256 + ty*32 + tx;
    bqkv[i] = (i<1024) ? bq[i] : ((i<2048) ? bk[i-1024] : bv[i-2048]);
    return;
  }
  const float* src; uint16_t* dst; int R, C, c0, r0;
  if (blk < 3072) {
    int w = blk>>10, tt = blk&1023;
    src = (w==0)?Wq:((w==1)?Wk:Wv); dst = wt_qkv + (size_t)w*1048576;
    R = 1024; C = 1024; c0 = (tt&31)*32; r0 = (tt>>5)*32;
  } else if (blk < 7168) {
    int tt = blk-3072;
    src = W1; dst = wt_w1; R = 1024; C = 4096;
    c0 = (tt&127)*32; r0 = (tt>>7)*32;
  } else {
    int tt = blk-7168;
    src = W2; dst = wt_w2; R = 4096; C = 1024;
    c0 = (tt&31)*32; r0 = (tt>>5)*32;
  }
  #pragma unroll
  for (int i=0;i<4;i++) t[ty+8*i][tx] = src[(size_t)(r0+ty+8*i)*C + c0+tx];
  __syncthreads();
  #pragma unroll
  for (int i=0;i<4;i++) dst[(size_t)(c0+ty+8*i)*R + r0+tx] = f2bf(t[tx][ty+8*i]);
}

// ---------------------------------------------------------------------------
extern "C" void kernel_launch(void* const* d_in, const int* in_sizes, int n_in,
                              void* d_out, int out_size, void* d_ws, size_t ws_size,
                              hipStream_t stream) {
  const float* input  = (const float*)d_in[0];
  const float* lnin_s = (const float*)d_in[1];
  const float* lnin_b = (const float*)d_in[2];
  const float* Wq = (const float*)d_in[3];
  const float* bq = (const float*)d_in[4];
  const float* Wk = (const float*)d_in[5];
  const float* bk = (const float*)d_in[6];
  const float* Wv = (const float*)d_in[7];
  const float* bv = (const float*)d_in[8];
  const float* ln1_s = (const float*)d_in[9];
  const float* ln1_b = (const float*)d_in[10];
  const float* W1 = (const float*)d_in[11];
  const float* b1 = (const float*)d_in[12];
  const float* W2 = (const float*)d_in[13];
  const float* b2 = (const float*)d_in[14];
  const float* ln2_s = (const float*)d_in[15];
  const float* ln2_b = (const float*)d_in[16];
  // mask d_in[17] unused: Emformer mask is closed-form.

  char* ws = (char*)d_ws;
  uint16_t* wt_qkv = (uint16_t*)(ws + 0);         // bf16 [3072][1024]
  uint16_t* wt_w1  = (uint16_t*)(ws + 6291456);   // bf16 [4096][1024]
  uint16_t* wt_w2  = (uint16_t*)(ws + 14680064);  // bf16 [1024][4096]
  float*    bqkv   = (float*)   (ws + 23068672);  // f32  [3072]
  uint16_t* hbuf   = (uint16_t*)(ws + 23080960);  // bf16 [2560][1024]
  uint16_t* qkvb   = (uint16_t*)(ws + 28323840);  // bf16 [2560][3072]
  uint16_t* attnb  = (uint16_t*)(ws + 44052480);  // bf16 [2560][1024]
  uint16_t* zbuf   = (uint16_t*)(ws + 49295360);  // bf16 [2560][1024]
  float*    pbuf   = (float*)   (ws + 54538240);  // fp32 [2][2560][1024] (probs now LDS-only)
  uint16_t* y1b    = hbuf;                        // bf16 [2560][4096] overlays hbuf+qkvb (dead)
  uint16_t* x1b    = zbuf;                        // layer-0 out overlays zbuf (dead at ln2;
                                                  // consumed by layer-1 ln_k before rewrite)
  // peak ws usage: 75,509,760 bytes

  const uint16_t* xcur_bf = x1b;
  for (int l=0; l<2; ++l) {
    prep_k<<<11276, dim3(32,8), 0, stream>>>(Wq+(size_t)l*1048576, Wk+(size_t)l*1048576,
        Wv+(size_t)l*1048576, W1+(size_t)l*4194304, W2+(size_t)l*4194304,
        bq+l*1024, bk+l*1024, bv+l*1024, wt_qkv, wt_w1, wt_w2, bqkv);

    if (l==0) ln_k<float,uint16_t>   <<<2496,256,0,stream>>>(input,   lnin_s+l*1024, lnin_b+l*1024, hbuf);
    else      ln_k<uint16_t,uint16_t><<<2496,256,0,stream>>>(xcur_bf, lnin_s+l*1024, lnin_b+l*1024, hbuf);
    gemm_t<64,false><<<dim3(24,40),256,0,stream>>>(hbuf, wt_qkv, bqkv, qkvb, 3072, 1024, 1024);
    attn_fused<<<1024,256,0,stream>>>((const uint32_t*)qkvb, hbuf, attnb);
    ln_k<uint16_t,uint16_t><<<2496,256,0,stream>>>(attnb, ln1_s+l*1024, ln1_b+l*1024, zbuf);
    gemm_t<64,false><<<dim3(32,40),256,0,stream>>>(zbuf, wt_w1, b1+l*4096, y1b, 4096, 1024, 1024);
    gemm_t<64,true><<<dim3(8,40,2),256,0,stream>>>(y1b, wt_w2, nullptr, pbuf, 1024, 4096, 2048);
    if (l==1) ln2_fused<float>   <<<2496,256,0,stream>>>(pbuf, b2+l*1024, attnb, ln2_s+l*1024, ln2_b+l*1024, (float*)d_out);
    else      ln2_fused<uint16_t><<<2496,256,0,stream>>>(pbuf, b2+l*1024, attnb, ln2_s+l*1024, ln2_b+l*1024, x1b);
  }
  (void)in_sizes; (void)n_in; (void)out_size; (void)ws_size;
}

// Round 6
// 532.902 us; speedup vs baseline: 1.3970x; 1.1173x over previous
//
#include <hip/hip_runtime.h>
#include <stdint.h>

typedef __attribute__((ext_vector_type(8))) short short8;
typedef __attribute__((ext_vector_type(4))) float f32x4;
typedef __attribute__((ext_vector_type(2))) _Float16 half2_t;

#define DEV __device__ __forceinline__

DEV float bits2f(uint32_t u){ union{uint32_t u;float f;}v; v.u=u; return v.f; }
DEV float bf_lo(uint32_t w){ return bits2f(w<<16); }
DEV float bf_hi(uint32_t w){ return bits2f(w & 0xffff0000u); }
DEV float bf1(uint16_t s){ return bits2f(((uint32_t)s)<<16); }
DEV uint16_t f2bf(float f){ union{float f;uint32_t u;}v; v.f=f; uint32_t u=v.u;
  return (uint16_t)((u + 0x7fffu + ((u>>16)&1u))>>16); }
DEV uint32_t pk16(float a, float b){ union{_Float16 h[2]; uint32_t u;}v;
  v.h[0]=(_Float16)a; v.h[1]=(_Float16)b; return v.u; }
DEV uint16_t f2h(float a){ union{_Float16 h; uint16_t u;}v; v.h=(_Float16)a; return v.u; }
DEV float h2f(uint16_t s){ union{uint16_t u; _Float16 h;}v; v.u=s; return (float)v.h; }

DEV float ldval(const float* p, size_t i){ return p[i]; }
DEV float ldval(const uint16_t* p, size_t i){ return bf1(p[i]); }
DEV void stval(float* p, size_t i, float v){ p[i]=v; }
DEV void stval(uint16_t* p, size_t i, float v){ p[i]=f2bf(v); }

DEV void async16(const void* g, void* l){
#if __has_builtin(__builtin_amdgcn_global_load_lds)
  __builtin_amdgcn_global_load_lds((const __attribute__((address_space(1))) void*)g,
                                   (__attribute__((address_space(3))) void*)l, 16, 0, 0);
#else
  int lane = threadIdx.x & 63;
  *(uint4*)((char*)l + lane*16) = *(const uint4*)((const char*)g);
#endif
}

// ---------------------------------------------------------------------------
// GEMM: C[M,N] = A[M,K] @ Bt[N,K]^T (+bias). Tile TM x 128, 4 waves.
// SPLIT: blockIdx.z K-chunking, fp32 partials at z*2560*N, no bias.
// ---------------------------------------------------------------------------
template<int TM, bool SPLIT>
__global__ __launch_bounds__(256) void gemm_t(
    const uint16_t* __restrict__ A, const uint16_t* __restrict__ Bt,
    const float* __restrict__ bias, void* __restrict__ Cout,
    int N, int K, int kchunk) {
  __shared__ uint16_t sA[TM*32];
  __shared__ uint16_t sB[128*32];
  const int m0 = blockIdx.y*TM, n0 = blockIdx.x*128;
  const int kb = SPLIT ? blockIdx.z*kchunk : 0;
  const int kend = SPLIT ? kb + kchunk : K;
  const int tid = threadIdx.x, wid = tid>>6, lane = tid&63;
  constexpr int WM = TM/2;
  constexpr int MT = WM/16;
  const int wm = (wid&1)*WM, wn = (wid>>1)*64;
  f32x4 acc[MT][4];
  #pragma unroll
  for (int a=0;a<MT;a++)
    #pragma unroll
    for (int b=0;b<4;b++) acc[a][b] = (f32x4){0.f,0.f,0.f,0.f};
  const int lrow = lane>>2, lcol = (lane&3)*8;

  for (int k0 = kb; k0 < kend; k0 += 32) {
    __syncthreads();
    #pragma unroll
    for (int j = 0; j < TM/64; ++j) {
      int r0 = wid*(TM/4) + j*16;
      async16(A + (size_t)(m0 + r0 + lrow)*K + k0 + lcol, &sA[r0*32]);
    }
    #pragma unroll
    for (int j = 0; j < 2; ++j) {
      int r0 = wid*32 + j*16;
      async16(Bt + (size_t)(n0 + r0 + lrow)*K + k0 + lcol, &sB[r0*32]);
    }
    __syncthreads();
    short8 af[MT], bfv[4];
    #pragma unroll
    for (int t=0;t<MT;t++) af[t] = *(const short8*)&sA[(wm + t*16 + (lane&15))*32 + (lane>>4)*8];
    #pragma unroll
    for (int t=0;t<4;t++)  bfv[t] = *(const short8*)&sB[(wn + t*16 + (lane&15))*32 + (lane>>4)*8];
    #pragma unroll
    for (int mt=0;mt<MT;mt++)
      #pragma unroll
      for (int nt=0;nt<4;nt++)
        acc[mt][nt] = __builtin_amdgcn_mfma_f32_16x16x32_bf16(af[mt], bfv[nt], acc[mt][nt], 0,0,0);
  }
  const int cl = lane&15, rl = (lane>>4)*4;
  if (SPLIT) {
    float* Pz = (float*)Cout + (size_t)blockIdx.z*2560*N;
    #pragma unroll
    for (int nt=0;nt<4;nt++) {
      int n = n0 + wn + nt*16 + cl;
      #pragma unroll
      for (int mt=0;mt<MT;mt++)
        #pragma unroll
        for (int r=0;r<4;r++)
          Pz[(size_t)(m0 + wm + mt*16 + rl + r)*N + n] = acc[mt][nt][r];
    }
  } else {
    uint16_t* C = (uint16_t*)Cout;
    #pragma unroll
    for (int nt=0;nt<4;nt++) {
      int n = n0 + wn + nt*16 + cl;
      float bv = bias ? bias[n] : 0.f;
      #pragma unroll
      for (int mt=0;mt<MT;mt++)
        #pragma unroll
        for (int r=0;r<4;r++)
          C[(size_t)(m0 + wm + mt*16 + rl + r)*N + n] = f2bf(acc[mt][nt][r] + bv);
    }
  }
}

// ---------------------------------------------------------------------------
// LayerNorm over D=1024, one block (256 thr) per row.
// ---------------------------------------------------------------------------
template<typename TI, typename TO>
__global__ __launch_bounds__(256) void ln_k(const TI* __restrict__ x,
    const float* __restrict__ sc, const float* __restrict__ bi,
    TO* __restrict__ out) {
  const int row = blockIdx.x, tid = threadIdx.x;
  const size_t base = (size_t)row*1024 + tid*4;
  float v0=ldval(x,base), v1=ldval(x,base+1), v2=ldval(x,base+2), v3=ldval(x,base+3);
  float s = v0+v1+v2+v3;
  float sq = v0*v0+v1*v1+v2*v2+v3*v3;
  #pragma unroll
  for (int off=32; off; off>>=1){ s += __shfl_xor(s,off); sq += __shfl_xor(sq,off); }
  __shared__ float red[8];
  int wid=tid>>6, lane=tid&63;
  if (lane==0){ red[wid]=s; red[4+wid]=sq; }
  __syncthreads();
  s = red[0]+red[1]+red[2]+red[3]; sq = red[4]+red[5]+red[6]+red[7];
  float mean = s*(1.f/1024.f);
  float inv  = rsqrtf(sq*(1.f/1024.f) - mean*mean + 1e-5f);
  int c = tid*4;
  stval(out, base,   (v0-mean)*inv*sc[c]   + bi[c]);
  stval(out, base+1, (v1-mean)*inv*sc[c+1] + bi[c+1]);
  stval(out, base+2, (v2-mean)*inv*sc[c+2] + bi[c+2]);
  stval(out, base+3, (v3-mean)*inv*sc[c+3] + bi[c+3]);
}

// Fused: y = P[0][row]+P[1][row] + b2 + resid(bf16); out = LN(y).
template<typename TO>
__global__ __launch_bounds__(256) void ln2_fused(const float* __restrict__ P,
    const float* __restrict__ b2, const uint16_t* __restrict__ resid,
    const float* __restrict__ sc, const float* __restrict__ bi,
    TO* __restrict__ out) {
  const int row = blockIdx.x, tid = threadIdx.x;
  const size_t base = (size_t)row*1024 + tid*4;
  float4 p0 = *(const float4*)(P + base);
  float4 p1 = *(const float4*)(P + (size_t)2560*1024 + base);
  int c = tid*4;
  float v0 = p0.x+p1.x+b2[c]  +bf1(resid[base]);
  float v1 = p0.y+p1.y+b2[c+1]+bf1(resid[base+1]);
  float v2 = p0.z+p1.z+b2[c+2]+bf1(resid[base+2]);
  float v3 = p0.w+p1.w+b2[c+3]+bf1(resid[base+3]);
  float s = v0+v1+v2+v3;
  float sq = v0*v0+v1*v1+v2*v2+v3*v3;
  #pragma unroll
  for (int off=32; off; off>>=1){ s += __shfl_xor(s,off); sq += __shfl_xor(sq,off); }
  __shared__ float red[8];
  int wid=tid>>6, lane=tid&63;
  if (lane==0){ red[wid]=s; red[4+wid]=sq; }
  __syncthreads();
  s = red[0]+red[1]+red[2]+red[3]; sq = red[4]+red[5]+red[6]+red[7];
  float mean = s*(1.f/1024.f);
  float inv  = rsqrtf(sq*(1.f/1024.f) - mean*mean + 1e-5f);
  stval(out, base,   (v0-mean)*inv*sc[c]   + bi[c]);
  stval(out, base+1, (v1-mean)*inv*sc[c+1] + bi[c+1]);
  stval(out, base+2, (v2-mean)*inv*sc[c+2] + bi[c+2]);
  stval(out, base+3, (v3-mean)*inv*sc[c+3] + bi[c+3]);
}

// ---------------------------------------------------------------------------
// Fused Emformer attention on MFMA f16. Closed-form mask.
// Block = (bb,hh,ci,qg): 40 queries, nk in {160,256,288} keys (all /16, /32).
// Phases: stage K,Q | S^T=K.Q^T (MFMA) | S->LDS | softmax->P | stage V^T | O=P.V.
// LDS: R1(20736h) = K[nk][72] -> S[40][296] -> VT[64][296];
//      R2(11840h) = Q[40][72] -> P[40][296].  Total 65,152 B, 2 blocks/CU.
// q n-tiles {0,16,24} overlap (rows 24..31 computed twice, identical) to
// cover 40 rows without padding. Frag-load idiom copied from verified gemm_t.
// ---------------------------------------------------------------------------
__global__ __launch_bounds__(256) void attn_fused(
    const uint32_t* __restrict__ qkv32, const uint16_t* __restrict__ hres,
    uint16_t* __restrict__ attn_out) {
  const int blk = blockIdx.x;
  const int qg = blk & 3, ci = (blk>>2)&7, hh = (blk>>5)&15, bb = blk>>9;
  const int sum_cnt = (ci<7)?32:0;
  const int bstart = (ci>=1)?128*(ci-1):0;
  const int bend = (ci==7)?1024:128*(ci+1);
  const int nk = sum_cnt + (bend - bstart);
  const int rowbase = bb*1248;
  const int tid = threadIdx.x, wid = tid>>6, lane = tid&63;
  const int fr = lane&15, fc = lane>>4;

  __shared__ uint16_t sm[32576];
  uint16_t* K16 = sm;                      // [nk][72]
  uint32_t* KD  = (uint32_t*)sm;           // stride 36 dw
  uint16_t* Q16 = sm + 20736;              // [40][72]
  uint32_t* QD  = (uint32_t*)(sm + 20736);
  uint16_t* S16 = sm;                      // [40][296] alias K (after barrier)
  uint16_t* P16 = sm + 20736;              // [40][296] alias Q (after barrier)
  uint16_t* VT16 = sm;                     // [64][296] alias S (after barrier)

  // ---- stage K, Q (f16) ----
  for (int idx = tid; idx < nk*32; idx += 256) {
    int j = idx>>5, d2 = idx&31;
    int tk = (j < sum_cnt) ? (32*ci + j) : (224 + bstart + (j - sum_cnt));
    uint32_t u = qkv32[(size_t)(rowbase+tk)*1536 + 512 + hh*32 + d2];
    KD[j*36 + d2] = pk16(bf_lo(u), bf_hi(u));
  }
  for (int idx = tid; idx < 40*32; idx += 256) {
    int j = idx>>5, d2 = idx&31;
    int ql = qg*40 + j;
    int tq = (ql<32) ? (32*ci+ql) : (224+128*ci+ql-32);
    uint32_t u = qkv32[(size_t)(rowbase+tq)*1536 + hh*32 + d2];
    QD[j*36 + d2] = pk16(bf_lo(u), bf_hi(u));
  }
  __syncthreads();

  // ---- scores: S^T = K . Q^T  (m=key, n=query, k=d) ----
  const int n_mt = nk>>4;
  const int qoff[3] = {0,16,24};
  f32x4 accs[5][3];
  #pragma unroll
  for (int a=0;a<5;a++)
    #pragma unroll
    for (int b=0;b<3;b++) accs[a][b] = (f32x4){0.f,0.f,0.f,0.f};
  #pragma unroll
  for (int ks=0; ks<2; ++ks) {
    short8 bq_[3];
    #pragma unroll
    for (int nt=0;nt<3;nt++)
      bq_[nt] = *(const short8*)&Q16[(qoff[nt]+fr)*72 + ks*32 + fc*8];
    #pragma unroll
    for (int t=0;t<5;t++) {
      int mt = wid + 4*t;
      if (mt < n_mt) {
        short8 a_ = *(const short8*)&K16[(mt*16+fr)*72 + ks*32 + fc*8];
        #pragma unroll
        for (int nt=0;nt<3;nt++)
          accs[t][nt] = __builtin_amdgcn_mfma_f32_16x16x32_f16(a_, bq_[nt], accs[t][nt], 0,0,0);
      }
    }
  }
  __syncthreads();   // all K/Q reads done; S may overwrite K region

  // ---- C-frags -> S[q][nk] f16 (scaled) ----
  #pragma unroll
  for (int t=0;t<5;t++) {
    int mt = wid + 4*t;
    if (mt < n_mt) {
      #pragma unroll
      for (int nt=0;nt<3;nt++) {
        int q = qoff[nt] + fr;              // C col = query
        #pragma unroll
        for (int r=0;r<4;r++)               // C row = key
          S16[q*296 + mt*16 + fc*4 + r] = f2h(accs[t][nt][r]*0.125f);
      }
    }
  }
  __syncthreads();

  // ---- softmax rows -> P[q][nk] f16 ----
  for (int i=0;i<10;i++) {
    int row = wid*10 + i;
    float v[5];
    #pragma unroll
    for (int g=0;g<5;g++){ int k=g*64+lane; v[g] = (k<nk) ? h2f(S16[row*296+k]) : -1e30f; }
    float mx = fmaxf(fmaxf(fmaxf(v[0],v[1]),fmaxf(v[2],v[3])),v[4]);
    #pragma unroll
    for (int off=32; off; off>>=1) mx = fmaxf(mx, __shfl_xor(mx,off));
    float p[5], sum=0.f;
    #pragma unroll
    for (int g=0;g<5;g++){ p[g] = __expf(v[g]-mx); if (g*64+lane>=nk) p[g]=0.f; sum+=p[g]; }
    #pragma unroll
    for (int off=32; off; off>>=1) sum += __shfl_xor(sum,off);
    float inv = 1.f/sum;
    #pragma unroll
    for (int g=0;g<5;g++){ int k=g*64+lane; if (k<nk) P16[row*296+k] = f2h(p[g]*inv); }
  }
  __syncthreads();   // S reads done; VT may overwrite

  // ---- stage V^T [d][nk] f16 ----
  for (int idx = tid; idx < nk*32; idx += 256) {
    int j = idx>>5, d2 = idx&31;
    int tk = (j < sum_cnt) ? (32*ci + j) : (224 + bstart + (j - sum_cnt));
    uint32_t u = qkv32[(size_t)(rowbase+tk)*1536 + 1024 + hh*32 + d2];
    VT16[(2*d2)*296 + j]   = f2h(bf_lo(u));
    VT16[(2*d2+1)*296 + j] = f2h(bf_hi(u));
  }
  __syncthreads();

  // ---- O = P . V  (m=query, n=d [wave-owned 16], k=key) ----
  const int nkt = nk>>5;
  f32x4 acco[3];
  #pragma unroll
  for (int t=0;t<3;t++) acco[t] = (f32x4){0.f,0.f,0.f,0.f};
  for (int kt=0; kt<nkt; ++kt) {
    short8 bv_ = *(const short8*)&VT16[(wid*16+fr)*296 + kt*32 + fc*8];
    #pragma unroll
    for (int t=0;t<3;t++) {
      short8 a_ = *(const short8*)&P16[(qoff[t]+fr)*296 + kt*32 + fc*8];
      acco[t] = __builtin_amdgcn_mfma_f32_16x16x32_f16(a_, bv_, acco[t], 0,0,0);
    }
  }
  // ---- epilogue: + residual, store (C col = d, row = query) ----
  #pragma unroll
  for (int t=0;t<3;t++) {
    #pragma unroll
    for (int r=0;r<4;r++) {
      int ql = qg*40 + qoff[t] + fc*4 + r;
      bool vq = (ci<7) || (ql >= qg*40+32) || (qg>0);
      // valid unless ci==7 and ql<32 (no summary queries in last chunk)
      if (ci==7 && qg==0 && (qoff[t]+fc*4+r)<32) vq = false; else vq = true;
      if (vq) {
        int qll = qg*40 + qoff[t] + fc*4 + r;
        int tq = (qll<32) ? (32*ci+qll) : (224+128*ci+qll-32);
        size_t addr = (size_t)(rowbase+tq)*1024 + hh*64 + wid*16 + fr;
        attn_out[addr] = f2bf(acco[t][r] + bf1(hres[addr]));
      }
      (void)ql;
    }
  }
}

// ---------------------------------------------------------------------------
// One-dispatch weight prep: transpose Wq,Wk,Wv,W1,W2 to bf16 [N][K] + bias cat.
// ---------------------------------------------------------------------------
__global__ void prep_k(const float* __restrict__ Wq, const float* __restrict__ Wk,
                       const float* __restrict__ Wv, const float* __restrict__ W1,
                       const float* __restrict__ W2, const float* __restrict__ bq,
                       const float* __restrict__ bk, const float* __restrict__ bv,
                       uint16_t* __restrict__ wt_qkv, uint16_t* __restrict__ wt_w1,
                       uint16_t* __restrict__ wt_w2, float* __restrict__ bqkv) {
  __shared__ float t[32][33];
  const int blk = blockIdx.x;
  const int tx = threadIdx.x, ty = threadIdx.y;
  if (blk >= 11264) {
    int i = (blk-11264)*256 + ty*32 + tx;
    bqkv[i] = (i<1024) ? bq[i] : ((i<2048) ? bk[i-1024] : bv[i-2048]);
    return;
  }
  const float* src; uint16_t* dst; int R, C, c0, r0;
  if (blk < 3072) {
    int w = blk>>10, tt = blk&1023;
    src = (w==0)?Wq:((w==1)?Wk:Wv); dst = wt_qkv + (size_t)w*1048576;
    R = 1024; C = 1024; c0 = (tt&31)*32; r0 = (tt>>5)*32;
  } else if (blk < 7168) {
    int tt = blk-3072;
    src = W1; dst = wt_w1; R = 1024; C = 4096;
    c0 = (tt&127)*32; r0 = (tt>>7)*32;
  } else {
    int tt = blk-7168;
    src = W2; dst = wt_w2; R = 4096; C = 1024;
    c0 = (tt&31)*32; r0 = (tt>>5)*32;
  }
  #pragma unroll
  for (int i=0;i<4;i++) t[ty+8*i][tx] = src[(size_t)(r0+ty+8*i)*C + c0+tx];
  __syncthreads();
  #pragma unroll
  for (int i=0;i<4;i++) dst[(size_t)(c0+ty+8*i)*R + r0+tx] = f2bf(t[tx][ty+8*i]);
}

// ---------------------------------------------------------------------------
extern "C" void kernel_launch(void* const* d_in, const int* in_sizes, int n_in,
                              void* d_out, int out_size, void* d_ws, size_t ws_size,
                              hipStream_t stream) {
  const float* input  = (const float*)d_in[0];
  const float* lnin_s = (const float*)d_in[1];
  const float* lnin_b = (const float*)d_in[2];
  const float* Wq = (const float*)d_in[3];
  const float* bq = (const float*)d_in[4];
  const float* Wk = (const float*)d_in[5];
  const float* bk = (const float*)d_in[6];
  const float* Wv = (const float*)d_in[7];
  const float* bv = (const float*)d_in[8];
  const float* ln1_s = (const float*)d_in[9];
  const float* ln1_b = (const float*)d_in[10];
  const float* W1 = (const float*)d_in[11];
  const float* b1 = (const float*)d_in[12];
  const float* W2 = (const float*)d_in[13];
  const float* b2 = (const float*)d_in[14];
  const float* ln2_s = (const float*)d_in[15];
  const float* ln2_b = (const float*)d_in[16];
  // mask d_in[17] unused: Emformer mask is closed-form.

  char* ws = (char*)d_ws;
  uint16_t* wt_qkv = (uint16_t*)(ws + 0);         // bf16 [3072][1024]
  uint16_t* wt_w1  = (uint16_t*)(ws + 6291456);   // bf16 [4096][1024]
  uint16_t* wt_w2  = (uint16_t*)(ws + 14680064);  // bf16 [1024][4096]
  float*    bqkv   = (float*)   (ws + 23068672);  // f32  [3072]
  uint16_t* hbuf   = (uint16_t*)(ws + 23080960);  // bf16 [2560][1024]
  uint16_t* qkvb   = (uint16_t*)(ws + 28323840);  // bf16 [2560][3072]
  uint16_t* attnb  = (uint16_t*)(ws + 44052480);  // bf16 [2560][1024]
  uint16_t* zbuf   = (uint16_t*)(ws + 49295360);  // bf16 [2560][1024]
  float*    pbuf   = (float*)   (ws + 54538240);  // fp32 [2][2560][1024]
  uint16_t* y1b    = hbuf;                        // bf16 [2560][4096] overlays hbuf+qkvb (dead)
  uint16_t* x1b    = zbuf;                        // layer-0 out overlays zbuf (audited r4)
  // peak ws usage: 75,509,760 bytes

  const uint16_t* xcur_bf = x1b;
  for (int l=0; l<2; ++l) {
    prep_k<<<11276, dim3(32,8), 0, stream>>>(Wq+(size_t)l*1048576, Wk+(size_t)l*1048576,
        Wv+(size_t)l*1048576, W1+(size_t)l*4194304, W2+(size_t)l*4194304,
        bq+l*1024, bk+l*1024, bv+l*1024, wt_qkv, wt_w1, wt_w2, bqkv);

    if (l==0) ln_k<float,uint16_t>   <<<2496,256,0,stream>>>(input,   lnin_s+l*1024, lnin_b+l*1024, hbuf);
    else      ln_k<uint16_t,uint16_t><<<2496,256,0,stream>>>(xcur_bf, lnin_s+l*1024, lnin_b+l*1024, hbuf);
    gemm_t<64,false><<<dim3(24,40),256,0,stream>>>(hbuf, wt_qkv, bqkv, qkvb, 3072, 1024, 1024);
    attn_fused<<<1024,256,0,stream>>>((const uint32_t*)qkvb, hbuf, attnb);
    ln_k<uint16_t,uint16_t><<<2496,256,0,stream>>>(attnb, ln1_s+l*1024, ln1_b+l*1024, zbuf);
    gemm_t<64,false><<<dim3(32,40),256,0,stream>>>(zbuf, wt_w1, b1+l*4096, y1b, 4096, 1024, 1024);
    gemm_t<64,true><<<dim3(8,40,2),256,0,stream>>>(y1b, wt_w2, nullptr, pbuf, 1024, 4096, 2048);
    if (l==1) ln2_fused<float>   <<<2496,256,0,stream>>>(pbuf, b2+l*1024, attnb, ln2_s+l*1024, ln2_b+l*1024, (float*)d_out);
    else      ln2_fused<uint16_t><<<2496,256,0,stream>>>(pbuf, b2+l*1024, attnb, ln2_s+l*1024, ln2_b+l*1024, x1b);
  }
  (void)in_sizes; (void)n_in; (void)out_size; (void)ws_size;
}

// Round 7
// 507.793 us; speedup vs baseline: 1.4661x; 1.0494x over previous
//
#include <hip/hip_runtime.h>
#include <stdint.h>

typedef __attribute__((ext_vector_type(8))) short short8;
typedef __attribute__((ext_vector_type(4))) float f32x4;
typedef __attribute__((ext_vector_type(2))) _Float16 half2_t;

#define DEV __device__ __forceinline__

DEV float bits2f(uint32_t u){ union{uint32_t u;float f;}v; v.u=u; return v.f; }
DEV float bf_lo(uint32_t w){ return bits2f(w<<16); }
DEV float bf_hi(uint32_t w){ return bits2f(w & 0xffff0000u); }
DEV float bf1(uint16_t s){ return bits2f(((uint32_t)s)<<16); }
DEV uint16_t f2bf(float f){ union{float f;uint32_t u;}v; v.f=f; uint32_t u=v.u;
  return (uint16_t)((u + 0x7fffu + ((u>>16)&1u))>>16); }
DEV uint32_t pk16(float a, float b){ union{_Float16 h[2]; uint32_t u;}v;
  v.h[0]=(_Float16)a; v.h[1]=(_Float16)b; return v.u; }
DEV uint16_t f2h(float a){ union{_Float16 h; uint16_t u;}v; v.h=(_Float16)a; return v.u; }
DEV float h2f(uint16_t s){ union{uint16_t u; _Float16 h;}v; v.u=s; return (float)v.h; }

DEV float ldval(const float* p, size_t i){ return p[i]; }
DEV float ldval(const uint16_t* p, size_t i){ return bf1(p[i]); }
DEV void stval(float* p, size_t i, float v){ p[i]=v; }
DEV void stval(uint16_t* p, size_t i, float v){ p[i]=f2bf(v); }

DEV void async16(const void* g, void* l){
#if __has_builtin(__builtin_amdgcn_global_load_lds)
  __builtin_amdgcn_global_load_lds((const __attribute__((address_space(1))) void*)g,
                                   (__attribute__((address_space(3))) void*)l, 16, 0, 0);
#else
  int lane = threadIdx.x & 63;
  *(uint4*)((char*)l + lane*16) = *(const uint4*)((const char*)g);
#endif
}

// ---------------------------------------------------------------------------
// GEMM: C[M,N] = A[M,K] @ Bt[N,K]^T (+bias). Tile TM x TN, 4 waves of
// (TM/2)x(TN/2). BK=64 staged as two 32-slices per barrier pair (halves the
// vmcnt(0)+barrier drains that dominate in the latency-bound regime).
// SPLIT: blockIdx.z K-chunking, fp32 partials at z*2560*N, no bias.
// ---------------------------------------------------------------------------
template<int TM, int TN, bool SPLIT>
__global__ __launch_bounds__(256) void gemm_t(
    const uint16_t* __restrict__ A, const uint16_t* __restrict__ Bt,
    const float* __restrict__ bias, void* __restrict__ Cout,
    int N, int K, int kchunk) {
  __shared__ uint16_t sA[2][TM*32];
  __shared__ uint16_t sB[2][TN*32];
  const int m0 = blockIdx.y*TM, n0 = blockIdx.x*TN;
  const int kb = SPLIT ? blockIdx.z*kchunk : 0;
  const int kend = SPLIT ? kb + kchunk : K;
  const int tid = threadIdx.x, wid = tid>>6, lane = tid&63;
  constexpr int WM = TM/2, MT = WM/16;
  constexpr int WN = TN/2, NT = WN/16;
  const int wm = (wid&1)*WM, wn = (wid>>1)*WN;
  f32x4 acc[MT][NT];
  #pragma unroll
  for (int a=0;a<MT;a++)
    #pragma unroll
    for (int b=0;b<NT;b++) acc[a][b] = (f32x4){0.f,0.f,0.f,0.f};
  const int lrow = lane>>2, lcol = (lane&3)*8;

  for (int k0 = kb; k0 < kend; k0 += 64) {
    __syncthreads();
    #pragma unroll
    for (int h=0; h<2; ++h) {
      #pragma unroll
      for (int j = 0; j < TM/64; ++j) {
        int r0 = wid*(TM/4) + j*16;
        async16(A + (size_t)(m0+r0+lrow)*K + k0+h*32 + lcol, &sA[h][r0*32]);
      }
      #pragma unroll
      for (int j = 0; j < TN/64; ++j) {
        int r0 = wid*(TN/4) + j*16;
        async16(Bt + (size_t)(n0+r0+lrow)*K + k0+h*32 + lcol, &sB[h][r0*32]);
      }
    }
    __syncthreads();
    #pragma unroll
    for (int h=0; h<2; ++h) {
      short8 af[MT], bfv[NT];
      #pragma unroll
      for (int t=0;t<MT;t++) af[t] = *(const short8*)&sA[h][(wm + t*16 + (lane&15))*32 + (lane>>4)*8];
      #pragma unroll
      for (int t=0;t<NT;t++) bfv[t] = *(const short8*)&sB[h][(wn + t*16 + (lane&15))*32 + (lane>>4)*8];
      #pragma unroll
      for (int mt=0;mt<MT;mt++)
        #pragma unroll
        for (int nt=0;nt<NT;nt++)
          acc[mt][nt] = __builtin_amdgcn_mfma_f32_16x16x32_bf16(af[mt], bfv[nt], acc[mt][nt], 0,0,0);
    }
  }
  const int cl = lane&15, rl = (lane>>4)*4;   // C/D: col=lane&15, row=(lane>>4)*4+reg
  if (SPLIT) {
    float* Pz = (float*)Cout + (size_t)blockIdx.z*2560*N;
    #pragma unroll
    for (int nt=0;nt<NT;nt++) {
      int n = n0 + wn + nt*16 + cl;
      #pragma unroll
      for (int mt=0;mt<MT;mt++)
        #pragma unroll
        for (int r=0;r<4;r++)
          Pz[(size_t)(m0 + wm + mt*16 + rl + r)*N + n] = acc[mt][nt][r];
    }
  } else {
    uint16_t* C = (uint16_t*)Cout;
    #pragma unroll
    for (int nt=0;nt<NT;nt++) {
      int n = n0 + wn + nt*16 + cl;
      float bv = bias ? bias[n] : 0.f;
      #pragma unroll
      for (int mt=0;mt<MT;mt++)
        #pragma unroll
        for (int r=0;r<4;r++)
          C[(size_t)(m0 + wm + mt*16 + rl + r)*N + n] = f2bf(acc[mt][nt][r] + bv);
    }
  }
}

// ---------------------------------------------------------------------------
// LayerNorm body (256-thread flat block, one row of D=1024).
// ---------------------------------------------------------------------------
template<typename TI, typename TO>
DEV void ln_body(int row, int tid, const TI* x, const float* sc, const float* bi,
                 TO* out, float* red) {
  const size_t base = (size_t)row*1024 + tid*4;
  float v0=ldval(x,base), v1=ldval(x,base+1), v2=ldval(x,base+2), v3=ldval(x,base+3);
  float s = v0+v1+v2+v3;
  float sq = v0*v0+v1*v1+v2*v2+v3*v3;
  #pragma unroll
  for (int off=32; off; off>>=1){ s += __shfl_xor(s,off); sq += __shfl_xor(sq,off); }
  int wid=tid>>6, lane=tid&63;
  if (lane==0){ red[wid]=s; red[4+wid]=sq; }
  __syncthreads();
  s = red[0]+red[1]+red[2]+red[3]; sq = red[4]+red[5]+red[6]+red[7];
  float mean = s*(1.f/1024.f);
  float inv  = rsqrtf(sq*(1.f/1024.f) - mean*mean + 1e-5f);
  int c = tid*4;
  stval(out, base,   (v0-mean)*inv*sc[c]   + bi[c]);
  stval(out, base+1, (v1-mean)*inv*sc[c+1] + bi[c+1]);
  stval(out, base+2, (v2-mean)*inv*sc[c+2] + bi[c+2]);
  stval(out, base+3, (v3-mean)*inv*sc[c+3] + bi[c+3]);
}

template<typename TI, typename TO>
__global__ __launch_bounds__(256) void ln_k(const TI* __restrict__ x,
    const float* __restrict__ sc, const float* __restrict__ bi,
    TO* __restrict__ out) {
  __shared__ float red[8];
  ln_body<TI,TO>(blockIdx.x, threadIdx.x, x, sc, bi, out, red);
}

// Fused: y = P[0][row]+P[1][row] + b2 + resid(bf16); out = LN(y).
template<typename TO>
__global__ __launch_bounds__(256) void ln2_fused(const float* __restrict__ P,
    const float* __restrict__ b2, const uint16_t* __restrict__ resid,
    const float* __restrict__ sc, const float* __restrict__ bi,
    TO* __restrict__ out) {
  const int row = blockIdx.x, tid = threadIdx.x;
  const size_t base = (size_t)row*1024 + tid*4;
  float4 p0 = *(const float4*)(P + base);
  float4 p1 = *(const float4*)(P + (size_t)2560*1024 + base);
  int c = tid*4;
  float v0 = p0.x+p1.x+b2[c]  +bf1(resid[base]);
  float v1 = p0.y+p1.y+b2[c+1]+bf1(resid[base+1]);
  float v2 = p0.z+p1.z+b2[c+2]+bf1(resid[base+2]);
  float v3 = p0.w+p1.w+b2[c+3]+bf1(resid[base+3]);
  float s = v0+v1+v2+v3;
  float sq = v0*v0+v1*v1+v2*v2+v3*v3;
  #pragma unroll
  for (int off=32; off; off>>=1){ s += __shfl_xor(s,off); sq += __shfl_xor(sq,off); }
  __shared__ float red[8];
  int wid=tid>>6, lane=tid&63;
  if (lane==0){ red[wid]=s; red[4+wid]=sq; }
  __syncthreads();
  s = red[0]+red[1]+red[2]+red[3]; sq = red[4]+red[5]+red[6]+red[7];
  float mean = s*(1.f/1024.f);
  float inv  = rsqrtf(sq*(1.f/1024.f) - mean*mean + 1e-5f);
  stval(out, base,   (v0-mean)*inv*sc[c]   + bi[c]);
  stval(out, base+1, (v1-mean)*inv*sc[c+1] + bi[c+1]);
  stval(out, base+2, (v2-mean)*inv*sc[c+2] + bi[c+2]);
  stval(out, base+3, (v3-mean)*inv*sc[c+3] + bi[c+3]);
}

// ---------------------------------------------------------------------------
// Fused Emformer attention on MFMA f16 (round-6, verified). Closed-form mask.
// ---------------------------------------------------------------------------
__global__ __launch_bounds__(256) void attn_fused(
    const uint32_t* __restrict__ qkv32, const uint16_t* __restrict__ hres,
    uint16_t* __restrict__ attn_out) {
  const int blk = blockIdx.x;
  const int qg = blk & 3, ci = (blk>>2)&7, hh = (blk>>5)&15, bb = blk>>9;
  const int sum_cnt = (ci<7)?32:0;
  const int bstart = (ci>=1)?128*(ci-1):0;
  const int bend = (ci==7)?1024:128*(ci+1);
  const int nk = sum_cnt + (bend - bstart);
  const int rowbase = bb*1248;
  const int tid = threadIdx.x, wid = tid>>6, lane = tid&63;
  const int fr = lane&15, fc = lane>>4;

  __shared__ uint16_t sm[32576];
  uint16_t* K16 = sm;                      // [nk][72]
  uint32_t* KD  = (uint32_t*)sm;
  uint16_t* Q16 = sm + 20736;              // [40][72]
  uint32_t* QD  = (uint32_t*)(sm + 20736);
  uint16_t* S16 = sm;                      // [40][296] alias K
  uint16_t* P16 = sm + 20736;              // [40][296] alias Q
  uint16_t* VT16 = sm;                     // [64][296] alias S

  for (int idx = tid; idx < nk*32; idx += 256) {
    int j = idx>>5, d2 = idx&31;
    int tk = (j < sum_cnt) ? (32*ci + j) : (224 + bstart + (j - sum_cnt));
    uint32_t u = qkv32[(size_t)(rowbase+tk)*1536 + 512 + hh*32 + d2];
    KD[j*36 + d2] = pk16(bf_lo(u), bf_hi(u));
  }
  for (int idx = tid; idx < 40*32; idx += 256) {
    int j = idx>>5, d2 = idx&31;
    int ql = qg*40 + j;
    int tq = (ql<32) ? (32*ci+ql) : (224+128*ci+ql-32);
    uint32_t u = qkv32[(size_t)(rowbase+tq)*1536 + hh*32 + d2];
    QD[j*36 + d2] = pk16(bf_lo(u), bf_hi(u));
  }
  __syncthreads();

  const int n_mt = nk>>4;
  const int qoff[3] = {0,16,24};
  f32x4 accs[5][3];
  #pragma unroll
  for (int a=0;a<5;a++)
    #pragma unroll
    for (int b=0;b<3;b++) accs[a][b] = (f32x4){0.f,0.f,0.f,0.f};
  #pragma unroll
  for (int ks=0; ks<2; ++ks) {
    short8 bq_[3];
    #pragma unroll
    for (int nt=0;nt<3;nt++)
      bq_[nt] = *(const short8*)&Q16[(qoff[nt]+fr)*72 + ks*32 + fc*8];
    #pragma unroll
    for (int t=0;t<5;t++) {
      int mt = wid + 4*t;
      if (mt < n_mt) {
        short8 a_ = *(const short8*)&K16[(mt*16+fr)*72 + ks*32 + fc*8];
        #pragma unroll
        for (int nt=0;nt<3;nt++)
          accs[t][nt] = __builtin_amdgcn_mfma_f32_16x16x32_f16(a_, bq_[nt], accs[t][nt], 0,0,0);
      }
    }
  }
  __syncthreads();

  #pragma unroll
  for (int t=0;t<5;t++) {
    int mt = wid + 4*t;
    if (mt < n_mt) {
      #pragma unroll
      for (int nt=0;nt<3;nt++) {
        int q = qoff[nt] + fr;
        #pragma unroll
        for (int r=0;r<4;r++)
          S16[q*296 + mt*16 + fc*4 + r] = f2h(accs[t][nt][r]*0.125f);
      }
    }
  }
  __syncthreads();

  for (int i=0;i<10;i++) {
    int row = wid*10 + i;
    float v[5];
    #pragma unroll
    for (int g=0;g<5;g++){ int k=g*64+lane; v[g] = (k<nk) ? h2f(S16[row*296+k]) : -1e30f; }
    float mx = fmaxf(fmaxf(fmaxf(v[0],v[1]),fmaxf(v[2],v[3])),v[4]);
    #pragma unroll
    for (int off=32; off; off>>=1) mx = fmaxf(mx, __shfl_xor(mx,off));
    float p[5], sum=0.f;
    #pragma unroll
    for (int g=0;g<5;g++){ p[g] = __expf(v[g]-mx); if (g*64+lane>=nk) p[g]=0.f; sum+=p[g]; }
    #pragma unroll
    for (int off=32; off; off>>=1) sum += __shfl_xor(sum,off);
    float inv = 1.f/sum;
    #pragma unroll
    for (int g=0;g<5;g++){ int k=g*64+lane; if (k<nk) P16[row*296+k] = f2h(p[g]*inv); }
  }
  __syncthreads();

  for (int idx = tid; idx < nk*32; idx += 256) {
    int j = idx>>5, d2 = idx&31;
    int tk = (j < sum_cnt) ? (32*ci + j) : (224 + bstart + (j - sum_cnt));
    uint32_t u = qkv32[(size_t)(rowbase+tk)*1536 + 1024 + hh*32 + d2];
    VT16[(2*d2)*296 + j]   = f2h(bf_lo(u));
    VT16[(2*d2+1)*296 + j] = f2h(bf_hi(u));
  }
  __syncthreads();

  const int nkt = nk>>5;
  f32x4 acco[3];
  #pragma unroll
  for (int t=0;t<3;t++) acco[t] = (f32x4){0.f,0.f,0.f,0.f};
  for (int kt=0; kt<nkt; ++kt) {
    short8 bv_ = *(const short8*)&VT16[(wid*16+fr)*296 + kt*32 + fc*8];
    #pragma unroll
    for (int t=0;t<3;t++) {
      short8 a_ = *(const short8*)&P16[(qoff[t]+fr)*296 + kt*32 + fc*8];
      acco[t] = __builtin_amdgcn_mfma_f32_16x16x32_f16(a_, bv_, acco[t], 0,0,0);
    }
  }
  #pragma unroll
  for (int t=0;t<3;t++) {
    #pragma unroll
    for (int r=0;r<4;r++) {
      bool vq = true;
      if (ci==7 && qg==0 && (qoff[t]+fc*4+r)<32) vq = false;
      if (vq) {
        int qll = qg*40 + qoff[t] + fc*4 + r;
        int tq = (qll<32) ? (32*ci+qll) : (224+128*ci+qll-32);
        size_t addr = (size_t)(rowbase+tq)*1024 + hh*64 + wid*16 + fr;
        attn_out[addr] = f2bf(acco[t][r] + bf1(hres[addr]));
      }
    }
  }
}

// ---------------------------------------------------------------------------
// One-dispatch layer prologue: weight transposes (blocks 0..11263), QKV bias
// concat (11264..11275), input LayerNorm rows (11276..13771).
// ---------------------------------------------------------------------------
__global__ void prep_k(const float* __restrict__ Wq, const float* __restrict__ Wk,
                       const float* __restrict__ Wv, const float* __restrict__ W1,
                       const float* __restrict__ W2, const float* __restrict__ bq,
                       const float* __restrict__ bk, const float* __restrict__ bv,
                       uint16_t* __restrict__ wt_qkv, uint16_t* __restrict__ wt_w1,
                       uint16_t* __restrict__ wt_w2, float* __restrict__ bqkv,
                       const void* __restrict__ lnx, int lnx_f32,
                       const float* __restrict__ lnsc, const float* __restrict__ lnbi,
                       uint16_t* __restrict__ lnout) {
  __shared__ float t[32][33];
  const int blk = blockIdx.x;
  const int tx = threadIdx.x, ty = threadIdx.y;
  if (blk >= 11276) {                       // LayerNorm rows
    int row = blk - 11276;
    int tid = ty*32 + tx;
    float* red = &t[0][0];
    if (lnx_f32) ln_body<float,uint16_t>((int)row, tid, (const float*)lnx, lnsc, lnbi, lnout, red);
    else         ln_body<uint16_t,uint16_t>((int)row, tid, (const uint16_t*)lnx, lnsc, lnbi, lnout, red);
    return;
  }
  if (blk >= 11264) {                       // bias concat
    int i = (blk-11264)*256 + ty*32 + tx;
    bqkv[i] = (i<1024) ? bq[i] : ((i<2048) ? bk[i-1024] : bv[i-2048]);
    return;
  }
  const float* src; uint16_t* dst; int R, C, c0, r0;
  if (blk < 3072) {
    int w = blk>>10, tt = blk&1023;
    src = (w==0)?Wq:((w==1)?Wk:Wv); dst = wt_qkv + (size_t)w*1048576;
    R = 1024; C = 1024; c0 = (tt&31)*32; r0 = (tt>>5)*32;
  } else if (blk < 7168) {
    int tt = blk-3072;
    src = W1; dst = wt_w1; R = 1024; C = 4096;
    c0 = (tt&127)*32; r0 = (tt>>7)*32;
  } else {
    int tt = blk-7168;
    src = W2; dst = wt_w2; R = 4096; C = 1024;
    c0 = (tt&31)*32; r0 = (tt>>5)*32;
  }
  #pragma unroll
  for (int i=0;i<4;i++) t[ty+8*i][tx] = src[(size_t)(r0+ty+8*i)*C + c0+tx];
  __syncthreads();
  #pragma unroll
  for (int i=0;i<4;i++) dst[(size_t)(c0+ty+8*i)*R + r0+tx] = f2bf(t[tx][ty+8*i]);
}

// ---------------------------------------------------------------------------
extern "C" void kernel_launch(void* const* d_in, const int* in_sizes, int n_in,
                              void* d_out, int out_size, void* d_ws, size_t ws_size,
                              hipStream_t stream) {
  const float* input  = (const float*)d_in[0];
  const float* lnin_s = (const float*)d_in[1];
  const float* lnin_b = (const float*)d_in[2];
  const float* Wq = (const float*)d_in[3];
  const float* bq = (const float*)d_in[4];
  const float* Wk = (const float*)d_in[5];
  const float* bk = (const float*)d_in[6];
  const float* Wv = (const float*)d_in[7];
  const float* bv = (const float*)d_in[8];
  const float* ln1_s = (const float*)d_in[9];
  const float* ln1_b = (const float*)d_in[10];
  const float* W1 = (const float*)d_in[11];
  const float* b1 = (const float*)d_in[12];
  const float* W2 = (const float*)d_in[13];
  const float* b2 = (const float*)d_in[14];
  const float* ln2_s = (const float*)d_in[15];
  const float* ln2_b = (const float*)d_in[16];
  // mask d_in[17] unused: Emformer mask is closed-form.

  char* ws = (char*)d_ws;
  uint16_t* wt_qkv = (uint16_t*)(ws + 0);         // bf16 [3072][1024]
  uint16_t* wt_w1  = (uint16_t*)(ws + 6291456);   // bf16 [4096][1024]
  uint16_t* wt_w2  = (uint16_t*)(ws + 14680064);  // bf16 [1024][4096]
  float*    bqkv   = (float*)   (ws + 23068672);  // f32  [3072]
  uint16_t* hbuf   = (uint16_t*)(ws + 23080960);  // bf16 [2560][1024]
  uint16_t* qkvb   = (uint16_t*)(ws + 28323840);  // bf16 [2560][3072]
  uint16_t* attnb  = (uint16_t*)(ws + 44052480);  // bf16 [2560][1024]
  uint16_t* zbuf   = (uint16_t*)(ws + 49295360);  // bf16 [2560][1024]
  float*    pbuf   = (float*)   (ws + 54538240);  // fp32 [2][2560][1024]
  uint16_t* y1b    = hbuf;                        // bf16 [2560][4096] overlays hbuf+qkvb (dead)
  uint16_t* x1b    = zbuf;                        // layer-0 out overlays zbuf (audited r4)
  // peak ws usage: 75,509,760 bytes

  const uint16_t* xcur_bf = x1b;
  for (int l=0; l<2; ++l) {
    // prologue: weight prep + input LN in one dispatch
    prep_k<<<13772, dim3(32,8), 0, stream>>>(Wq+(size_t)l*1048576, Wk+(size_t)l*1048576,
        Wv+(size_t)l*1048576, W1+(size_t)l*4194304, W2+(size_t)l*4194304,
        bq+l*1024, bk+l*1024, bv+l*1024, wt_qkv, wt_w1, wt_w2, bqkv,
        (l==0) ? (const void*)input : (const void*)xcur_bf, (l==0)?1:0,
        lnin_s+l*1024, lnin_b+l*1024, hbuf);

    gemm_t<64,128,false><<<dim3(24,40),256,0,stream>>>(hbuf, wt_qkv, bqkv, qkvb, 3072, 1024, 1024);
    attn_fused<<<1024,256,0,stream>>>((const uint32_t*)qkvb, hbuf, attnb);
    ln_k<uint16_t,uint16_t><<<2496,256,0,stream>>>(attnb, ln1_s+l*1024, ln1_b+l*1024, zbuf);
    gemm_t<64,128,false><<<dim3(32,40),256,0,stream>>>(zbuf, wt_w1, b1+l*4096, y1b, 4096, 1024, 1024);
    gemm_t<64,64,true><<<dim3(16,40,2),256,0,stream>>>(y1b, wt_w2, nullptr, pbuf, 1024, 4096, 2048);
    if (l==1) ln2_fused<float>   <<<2496,256,0,stream>>>(pbuf, b2+l*1024, attnb, ln2_s+l*1024, ln2_b+l*1024, (float*)d_out);
    else      ln2_fused<uint16_t><<<2496,256,0,stream>>>(pbuf, b2+l*1024, attnb, ln2_s+l*1024, ln2_b+l*1024, x1b);
  }
  (void)in_sizes; (void)n_in; (void)out_size; (void)ws_size;
}

// Round 8
// 507.392 us; speedup vs baseline: 1.4672x; 1.0008x over previous
//
#include <hip/hip_runtime.h>
#include <stdint.h>

typedef __attribute__((ext_vector_type(8))) short short8;
typedef __attribute__((ext_vector_type(4))) float f32x4;
typedef __attribute__((ext_vector_type(2))) _Float16 half2_t;

#define DEV __device__ __forceinline__

DEV float bits2f(uint32_t u){ union{uint32_t u;float f;}v; v.u=u; return v.f; }
DEV float bf_lo(uint32_t w){ return bits2f(w<<16); }
DEV float bf_hi(uint32_t w){ return bits2f(w & 0xffff0000u); }
DEV float bf1(uint16_t s){ return bits2f(((uint32_t)s)<<16); }
DEV uint16_t f2bf(float f){ union{float f;uint32_t u;}v; v.f=f; uint32_t u=v.u;
  return (uint16_t)((u + 0x7fffu + ((u>>16)&1u))>>16); }
DEV uint16_t f2h(float a){ union{_Float16 h; uint16_t u;}v; v.h=(_Float16)a; return v.u; }
DEV float h2f(uint16_t s){ union{uint16_t u; _Float16 h;}v; v.u=s; return (float)v.h; }

DEV float ldval(const float* p, size_t i){ return p[i]; }
DEV float ldval(const uint16_t* p, size_t i){ return bf1(p[i]); }
DEV void stval(float* p, size_t i, float v){ p[i]=v; }
DEV void stval(uint16_t* p, size_t i, float v){ p[i]=f2bf(v); }

DEV void async16(const void* g, void* l){
#if __has_builtin(__builtin_amdgcn_global_load_lds)
  __builtin_amdgcn_global_load_lds((const __attribute__((address_space(1))) void*)g,
                                   (__attribute__((address_space(3))) void*)l, 16, 0, 0);
#else
  int lane = threadIdx.x & 63;
  *(uint4*)((char*)l + lane*16) = *(const uint4*)((const char*)g);
#endif
}

// ---------------------------------------------------------------------------
// GEMM: C[M,N] = A[M,K] @ Bt[N,K]^T (+bias). Tile TM x TN, 4 waves of
// (TM/2)x(TN/2). BK=64 staged as two 32-slices per barrier pair.
// SPLIT: blockIdx.z K-chunking, fp32 partials at z*2560*N, no bias.
// ---------------------------------------------------------------------------
template<int TM, int TN, bool SPLIT>
__global__ __launch_bounds__(256) void gemm_t(
    const uint16_t* __restrict__ A, const uint16_t* __restrict__ Bt,
    const float* __restrict__ bias, void* __restrict__ Cout,
    int N, int K, int kchunk) {
  __shared__ uint16_t sA[2][TM*32];
  __shared__ uint16_t sB[2][TN*32];
  const int m0 = blockIdx.y*TM, n0 = blockIdx.x*TN;
  const int kb = SPLIT ? blockIdx.z*kchunk : 0;
  const int kend = SPLIT ? kb + kchunk : K;
  const int tid = threadIdx.x, wid = tid>>6, lane = tid&63;
  constexpr int WM = TM/2, MT = WM/16;
  constexpr int WN = TN/2, NT = WN/16;
  const int wm = (wid&1)*WM, wn = (wid>>1)*WN;
  f32x4 acc[MT][NT];
  #pragma unroll
  for (int a=0;a<MT;a++)
    #pragma unroll
    for (int b=0;b<NT;b++) acc[a][b] = (f32x4){0.f,0.f,0.f,0.f};
  const int lrow = lane>>2, lcol = (lane&3)*8;

  for (int k0 = kb; k0 < kend; k0 += 64) {
    __syncthreads();
    #pragma unroll
    for (int h=0; h<2; ++h) {
      #pragma unroll
      for (int j = 0; j < TM/64; ++j) {
        int r0 = wid*(TM/4) + j*16;
        async16(A + (size_t)(m0+r0+lrow)*K + k0+h*32 + lcol, &sA[h][r0*32]);
      }
      #pragma unroll
      for (int j = 0; j < TN/64; ++j) {
        int r0 = wid*(TN/4) + j*16;
        async16(Bt + (size_t)(n0+r0+lrow)*K + k0+h*32 + lcol, &sB[h][r0*32]);
      }
    }
    __syncthreads();
    #pragma unroll
    for (int h=0; h<2; ++h) {
      short8 af[MT], bfv[NT];
      #pragma unroll
      for (int t=0;t<MT;t++) af[t] = *(const short8*)&sA[h][(wm + t*16 + (lane&15))*32 + (lane>>4)*8];
      #pragma unroll
      for (int t=0;t<NT;t++) bfv[t] = *(const short8*)&sB[h][(wn + t*16 + (lane&15))*32 + (lane>>4)*8];
      #pragma unroll
      for (int mt=0;mt<MT;mt++)
        #pragma unroll
        for (int nt=0;nt<NT;nt++)
          acc[mt][nt] = __builtin_amdgcn_mfma_f32_16x16x32_bf16(af[mt], bfv[nt], acc[mt][nt], 0,0,0);
    }
  }
  const int cl = lane&15, rl = (lane>>4)*4;   // C/D: col=lane&15, row=(lane>>4)*4+reg
  if (SPLIT) {
    float* Pz = (float*)Cout + (size_t)blockIdx.z*2560*N;
    #pragma unroll
    for (int nt=0;nt<NT;nt++) {
      int n = n0 + wn + nt*16 + cl;
      #pragma unroll
      for (int mt=0;mt<MT;mt++)
        #pragma unroll
        for (int r=0;r<4;r++)
          Pz[(size_t)(m0 + wm + mt*16 + rl + r)*N + n] = acc[mt][nt][r];
    }
  } else {
    uint16_t* C = (uint16_t*)Cout;
    #pragma unroll
    for (int nt=0;nt<NT;nt++) {
      int n = n0 + wn + nt*16 + cl;
      float bv = bias ? bias[n] : 0.f;
      #pragma unroll
      for (int mt=0;mt<MT;mt++)
        #pragma unroll
        for (int r=0;r<4;r++)
          C[(size_t)(m0 + wm + mt*16 + rl + r)*N + n] = f2bf(acc[mt][nt][r] + bv);
    }
  }
}

// ---------------------------------------------------------------------------
// LayerNorm body (256-thread flat block, one row of D=1024).
// ---------------------------------------------------------------------------
template<typename TI, typename TO>
DEV void ln_body(int row, int tid, const TI* x, const float* sc, const float* bi,
                 TO* out, float* red) {
  const size_t base = (size_t)row*1024 + tid*4;
  float v0=ldval(x,base), v1=ldval(x,base+1), v2=ldval(x,base+2), v3=ldval(x,base+3);
  float s = v0+v1+v2+v3;
  float sq = v0*v0+v1*v1+v2*v2+v3*v3;
  #pragma unroll
  for (int off=32; off; off>>=1){ s += __shfl_xor(s,off); sq += __shfl_xor(sq,off); }
  int wid=tid>>6, lane=tid&63;
  if (lane==0){ red[wid]=s; red[4+wid]=sq; }
  __syncthreads();
  s = red[0]+red[1]+red[2]+red[3]; sq = red[4]+red[5]+red[6]+red[7];
  float mean = s*(1.f/1024.f);
  float inv  = rsqrtf(sq*(1.f/1024.f) - mean*mean + 1e-5f);
  int c = tid*4;
  stval(out, base,   (v0-mean)*inv*sc[c]   + bi[c]);
  stval(out, base+1, (v1-mean)*inv*sc[c+1] + bi[c+1]);
  stval(out, base+2, (v2-mean)*inv*sc[c+2] + bi[c+2]);
  stval(out, base+3, (v3-mean)*inv*sc[c+3] + bi[c+3]);
}

template<typename TI, typename TO>
__global__ __launch_bounds__(256) void ln_k(const TI* __restrict__ x,
    const float* __restrict__ sc, const float* __restrict__ bi,
    TO* __restrict__ out) {
  __shared__ float red[8];
  ln_body<TI,TO>(blockIdx.x, threadIdx.x, x, sc, bi, out, red);
}

// Fused: y = P[0][row]+P[1][row] + b2 + resid(bf16); out = LN(y).
template<typename TO>
__global__ __launch_bounds__(256) void ln2_fused(const float* __restrict__ P,
    const float* __restrict__ b2, const uint16_t* __restrict__ resid,
    const float* __restrict__ sc, const float* __restrict__ bi,
    TO* __restrict__ out) {
  const int row = blockIdx.x, tid = threadIdx.x;
  const size_t base = (size_t)row*1024 + tid*4;
  float4 p0 = *(const float4*)(P + base);
  float4 p1 = *(const float4*)(P + (size_t)2560*1024 + base);
  int c = tid*4;
  float v0 = p0.x+p1.x+b2[c]  +bf1(resid[base]);
  float v1 = p0.y+p1.y+b2[c+1]+bf1(resid[base+1]);
  float v2 = p0.z+p1.z+b2[c+2]+bf1(resid[base+2]);
  float v3 = p0.w+p1.w+b2[c+3]+bf1(resid[base+3]);
  float s = v0+v1+v2+v3;
  float sq = v0*v0+v1*v1+v2*v2+v3*v3;
  #pragma unroll
  for (int off=32; off; off>>=1){ s += __shfl_xor(s,off); sq += __shfl_xor(sq,off); }
  __shared__ float red[8];
  int wid=tid>>6, lane=tid&63;
  if (lane==0){ red[wid]=s; red[4+wid]=sq; }
  __syncthreads();
  s = red[0]+red[1]+red[2]+red[3]; sq = red[4]+red[5]+red[6]+red[7];
  float mean = s*(1.f/1024.f);
  float inv  = rsqrtf(sq*(1.f/1024.f) - mean*mean + 1e-5f);
  stval(out, base,   (v0-mean)*inv*sc[c]   + bi[c]);
  stval(out, base+1, (v1-mean)*inv*sc[c+1] + bi[c+1]);
  stval(out, base+2, (v2-mean)*inv*sc[c+2] + bi[c+2]);
  stval(out, base+3, (v3-mean)*inv*sc[c+3] + bi[c+3]);
}

// ---------------------------------------------------------------------------
// Fused Emformer attention, bf16 MFMA end-to-end. Closed-form mask.
// Block = (bb,hh,ci,qg): 40 queries, nk in {160,256,288} keys.
// Staging = straight u32 copies (no dtype conversion). No V transpose:
// PV B-frags read V[nk][66] via 8 strided ds_read_u16 (2-way banks = free).
// S in f16, softmax in-place -> P bf16 (same buffer). V staged during the
// S-write phase (global latency overlaps compute). 5 barriers.
// LDS: phase1 K[288][72]@0 + Q[40][72]@20736h = 47,232 B;
//      phase2 S/P[40][296]@0 (23,680 B) + V[288][66]@11840h -> 61,696 B total.
// ---------------------------------------------------------------------------
__global__ __launch_bounds__(256) void attn_fused(
    const uint32_t* __restrict__ qkv32, const uint16_t* __restrict__ hres,
    uint16_t* __restrict__ attn_out) {
  const int blk = blockIdx.x;
  const int qg = blk & 3, ci = (blk>>2)&7, hh = (blk>>5)&15, bb = blk>>9;
  const int sum_cnt = (ci<7)?32:0;
  const int bstart = (ci>=1)?128*(ci-1):0;
  const int bend = (ci==7)?1024:128*(ci+1);
  const int nk = sum_cnt + (bend - bstart);
  const int rowbase = bb*1248;
  const int tid = threadIdx.x, wid = tid>>6, lane = tid&63;
  const int fr = lane&15, fc = lane>>4;

  __shared__ uint16_t sm[30848];           // 61,696 B
  uint16_t* K16 = sm;                      // [nk][72] bf16
  uint32_t* KD  = (uint32_t*)sm;           // stride 36 dw
  uint16_t* Q16 = sm + 20736;              // [40][72] bf16
  uint32_t* QD  = KD + 10368;
  uint16_t* SP16 = sm;                     // S f16 / P bf16 [40][296] (alias K head)
  uint16_t* V16 = sm + 11840;              // [nk][66] bf16 (alias K tail + Q)
  uint32_t* VD  = (uint32_t*)(sm + 11840); // stride 33 dw

  // ---- stage K, Q: straight u32 copies (bf16 pairs) ----
  for (int idx = tid; idx < nk*32; idx += 256) {
    int j = idx>>5, d2 = idx&31;
    int tk = (j < sum_cnt) ? (32*ci + j) : (224 + bstart + (j - sum_cnt));
    KD[j*36 + d2] = qkv32[(size_t)(rowbase+tk)*1536 + 512 + hh*32 + d2];
  }
  for (int idx = tid; idx < 40*32; idx += 256) {
    int j = idx>>5, d2 = idx&31;
    int ql = qg*40 + j;
    int tq = (ql<32) ? (32*ci+ql) : (224+128*ci+ql-32);
    QD[j*36 + d2] = qkv32[(size_t)(rowbase+tq)*1536 + hh*32 + d2];
  }
  __syncthreads();

  // ---- scores: S^T = K . Q^T (m=key, n=query, k=d), bf16 MFMA ----
  const int n_mt = nk>>4;
  const int qoff[3] = {0,16,24};
  f32x4 accs[5][3];
  #pragma unroll
  for (int a=0;a<5;a++)
    #pragma unroll
    for (int b=0;b<3;b++) accs[a][b] = (f32x4){0.f,0.f,0.f,0.f};
  #pragma unroll
  for (int ks=0; ks<2; ++ks) {
    short8 bq_[3];
    #pragma unroll
    for (int nt=0;nt<3;nt++)
      bq_[nt] = *(const short8*)&Q16[(qoff[nt]+fr)*72 + ks*32 + fc*8];
    #pragma unroll
    for (int t=0;t<5;t++) {
      int mt = wid + 4*t;
      if (mt < n_mt) {
        short8 a_ = *(const short8*)&K16[(mt*16+fr)*72 + ks*32 + fc*8];
        #pragma unroll
        for (int nt=0;nt<3;nt++)
          accs[t][nt] = __builtin_amdgcn_mfma_f32_16x16x32_bf16(a_, bq_[nt], accs[t][nt], 0,0,0);
      }
    }
  }
  __syncthreads();   // K/Q reads done; S and V regions may be written

  // ---- phase: S <- C-frags (f16), and stage V concurrently ----
  #pragma unroll
  for (int t=0;t<5;t++) {
    int mt = wid + 4*t;
    if (mt < n_mt) {
      #pragma unroll
      for (int nt=0;nt<3;nt++) {
        int q = qoff[nt] + fr;
        #pragma unroll
        for (int r=0;r<4;r++)
          SP16[q*296 + mt*16 + fc*4 + r] = f2h(accs[t][nt][r]*0.125f);
      }
    }
  }
  for (int idx = tid; idx < nk*32; idx += 256) {
    int j = idx>>5, d2 = idx&31;
    int tk = (j < sum_cnt) ? (32*ci + j) : (224 + bstart + (j - sum_cnt));
    VD[j*33 + d2] = qkv32[(size_t)(rowbase+tk)*1536 + 1024 + hh*32 + d2];
  }
  __syncthreads();

  // ---- softmax rows, in place: S(f16) -> P(bf16) ----
  for (int i=0;i<10;i++) {
    int row = wid*10 + i;
    float v[5];
    #pragma unroll
    for (int g=0;g<5;g++){ int k=g*64+lane; v[g] = (k<nk) ? h2f(SP16[row*296+k]) : -1e30f; }
    float mx = fmaxf(fmaxf(fmaxf(v[0],v[1]),fmaxf(v[2],v[3])),v[4]);
    #pragma unroll
    for (int off=32; off; off>>=1) mx = fmaxf(mx, __shfl_xor(mx,off));
    float p[5], sum=0.f;
    #pragma unroll
    for (int g=0;g<5;g++){ p[g] = __expf(v[g]-mx); if (g*64+lane>=nk) p[g]=0.f; sum+=p[g]; }
    #pragma unroll
    for (int off=32; off; off>>=1) sum += __shfl_xor(sum,off);
    float inv = 1.f/sum;
    #pragma unroll
    for (int g=0;g<5;g++){ int k=g*64+lane; if (k<nk) SP16[row*296+k] = f2bf(p[g]*inv); }
  }
  __syncthreads();

  // ---- O = P . V  (m=query, n=d [wave-owned 16], k=key), bf16 MFMA ----
  const int nkt = nk>>5;
  f32x4 acco[3];
  #pragma unroll
  for (int t=0;t<3;t++) acco[t] = (f32x4){0.f,0.f,0.f,0.f};
  const uint16_t* vcol = V16 + wid*16 + fr;
  for (int kt=0; kt<nkt; ++kt) {
    short8 bv_;
    #pragma unroll
    for (int j=0;j<8;j++) bv_[j] = (short)vcol[(kt*32 + fc*8 + j)*66];
    #pragma unroll
    for (int t=0;t<3;t++) {
      short8 a_ = *(const short8*)&SP16[(qoff[t]+fr)*296 + kt*32 + fc*8];
      acco[t] = __builtin_amdgcn_mfma_f32_16x16x32_bf16(a_, bv_, acco[t], 0,0,0);
    }
  }
  // ---- epilogue: + residual (C col = d, row = query) ----
  #pragma unroll
  for (int t=0;t<3;t++) {
    #pragma unroll
    for (int r=0;r<4;r++) {
      bool vq = true;
      if (ci==7 && qg==0 && (qoff[t]+fc*4+r)<32) vq = false;
      if (vq) {
        int qll = qg*40 + qoff[t] + fc*4 + r;
        int tq = (qll<32) ? (32*ci+qll) : (224+128*ci+qll-32);
        size_t addr = (size_t)(rowbase+tq)*1024 + hh*64 + wid*16 + fr;
        attn_out[addr] = f2bf(acco[t][r] + bf1(hres[addr]));
      }
    }
  }
}

// ---------------------------------------------------------------------------
// One-dispatch layer prologue: weight transposes (blocks 0..11263), QKV bias
// concat (11264..11275), input LayerNorm rows (11276..13771).
// ---------------------------------------------------------------------------
__global__ void prep_k(const float* __restrict__ Wq, const float* __restrict__ Wk,
                       const float* __restrict__ Wv, const float* __restrict__ W1,
                       const float* __restrict__ W2, const float* __restrict__ bq,
                       const float* __restrict__ bk, const float* __restrict__ bv,
                       uint16_t* __restrict__ wt_qkv, uint16_t* __restrict__ wt_w1,
                       uint16_t* __restrict__ wt_w2, float* __restrict__ bqkv,
                       const void* __restrict__ lnx, int lnx_f32,
                       const float* __restrict__ lnsc, const float* __restrict__ lnbi,
                       uint16_t* __restrict__ lnout) {
  __shared__ float t[32][33];
  const int blk = blockIdx.x;
  const int tx = threadIdx.x, ty = threadIdx.y;
  if (blk >= 11276) {                       // LayerNorm rows
    int row = blk - 11276;
    int tid = ty*32 + tx;
    float* red = &t[0][0];
    if (lnx_f32) ln_body<float,uint16_t>((int)row, tid, (const float*)lnx, lnsc, lnbi, lnout, red);
    else         ln_body<uint16_t,uint16_t>((int)row, tid, (const uint16_t*)lnx, lnsc, lnbi, lnout, red);
    return;
  }
  if (blk >= 11264) {                       // bias concat
    int i = (blk-11264)*256 + ty*32 + tx;
    bqkv[i] = (i<1024) ? bq[i] : ((i<2048) ? bk[i-1024] : bv[i-2048]);
    return;
  }
  const float* src; uint16_t* dst; int R, C, c0, r0;
  if (blk < 3072) {
    int w = blk>>10, tt = blk&1023;
    src = (w==0)?Wq:((w==1)?Wk:Wv); dst = wt_qkv + (size_t)w*1048576;
    R = 1024; C = 1024; c0 = (tt&31)*32; r0 = (tt>>5)*32;
  } else if (blk < 7168) {
    int tt = blk-3072;
    src = W1; dst = wt_w1; R = 1024; C = 4096;
    c0 = (tt&127)*32; r0 = (tt>>7)*32;
  } else {
    int tt = blk-7168;
    src = W2; dst = wt_w2; R = 4096; C = 1024;
    c0 = (tt&31)*32; r0 = (tt>>5)*32;
  }
  #pragma unroll
  for (int i=0;i<4;i++) t[ty+8*i][tx] = src[(size_t)(r0+ty+8*i)*C + c0+tx];
  __syncthreads();
  #pragma unroll
  for (int i=0;i<4;i++) dst[(size_t)(c0+ty+8*i)*R + r0+tx] = f2bf(t[tx][ty+8*i]);
}

// ---------------------------------------------------------------------------
extern "C" void kernel_launch(void* const* d_in, const int* in_sizes, int n_in,
                              void* d_out, int out_size, void* d_ws, size_t ws_size,
                              hipStream_t stream) {
  const float* input  = (const float*)d_in[0];
  const float* lnin_s = (const float*)d_in[1];
  const float* lnin_b = (const float*)d_in[2];
  const float* Wq = (const float*)d_in[3];
  const float* bq = (const float*)d_in[4];
  const float* Wk = (const float*)d_in[5];
  const float* bk = (const float*)d_in[6];
  const float* Wv = (const float*)d_in[7];
  const float* bv = (const float*)d_in[8];
  const float* ln1_s = (const float*)d_in[9];
  const float* ln1_b = (const float*)d_in[10];
  const float* W1 = (const float*)d_in[11];
  const float* b1 = (const float*)d_in[12];
  const float* W2 = (const float*)d_in[13];
  const float* b2 = (const float*)d_in[14];
  const float* ln2_s = (const float*)d_in[15];
  const float* ln2_b = (const float*)d_in[16];
  // mask d_in[17] unused: Emformer mask is closed-form.

  char* ws = (char*)d_ws;
  uint16_t* wt_qkv = (uint16_t*)(ws + 0);         // bf16 [3072][1024]
  uint16_t* wt_w1  = (uint16_t*)(ws + 6291456);   // bf16 [4096][1024]
  uint16_t* wt_w2  = (uint16_t*)(ws + 14680064);  // bf16 [1024][4096]
  float*    bqkv   = (float*)   (ws + 23068672);  // f32  [3072]
  uint16_t* hbuf   = (uint16_t*)(ws + 23080960);  // bf16 [2560][1024]
  uint16_t* qkvb   = (uint16_t*)(ws + 28323840);  // bf16 [2560][3072]
  uint16_t* attnb  = (uint16_t*)(ws + 44052480);  // bf16 [2560][1024]
  uint16_t* zbuf   = (uint16_t*)(ws + 49295360);  // bf16 [2560][1024]
  float*    pbuf   = (float*)   (ws + 54538240);  // fp32 [2][2560][1024]
  uint16_t* y1b    = hbuf;                        // bf16 [2560][4096] overlays hbuf+qkvb (dead)
  uint16_t* x1b    = zbuf;                        // layer-0 out overlays zbuf (audited r4)
  // peak ws usage: 75,509,760 bytes

  const uint16_t* xcur_bf = x1b;
  for (int l=0; l<2; ++l) {
    prep_k<<<13772, dim3(32,8), 0, stream>>>(Wq+(size_t)l*1048576, Wk+(size_t)l*1048576,
        Wv+(size_t)l*1048576, W1+(size_t)l*4194304, W2+(size_t)l*4194304,
        bq+l*1024, bk+l*1024, bv+l*1024, wt_qkv, wt_w1, wt_w2, bqkv,
        (l==0) ? (const void*)input : (const void*)xcur_bf, (l==0)?1:0,
        lnin_s+l*1024, lnin_b+l*1024, hbuf);

    gemm_t<64,128,false><<<dim3(24,40),256,0,stream>>>(hbuf, wt_qkv, bqkv, qkvb, 3072, 1024, 1024);
    attn_fused<<<1024,256,0,stream>>>((const uint32_t*)qkvb, hbuf, attnb);
    ln_k<uint16_t,uint16_t><<<2496,256,0,stream>>>(attnb, ln1_s+l*1024, ln1_b+l*1024, zbuf);
    gemm_t<64,128,false><<<dim3(32,40),256,0,stream>>>(zbuf, wt_w1, b1+l*4096, y1b, 4096, 1024, 1024);
    gemm_t<64,64,true><<<dim3(16,40,2),256,0,stream>>>(y1b, wt_w2, nullptr, pbuf, 1024, 4096, 2048);
    if (l==1) ln2_fused<float>   <<<2496,256,0,stream>>>(pbuf, b2+l*1024, attnb, ln2_s+l*1024, ln2_b+l*1024, (float*)d_out);
    else      ln2_fused<uint16_t><<<2496,256,0,stream>>>(pbuf, b2+l*1024, attnb, ln2_s+l*1024, ln2_b+l*1024, x1b);
  }
  (void)in_sizes; (void)n_in; (void)out_size; (void)ws_size;
}